// Round 2
// baseline (3081.408 us; speedup 1.0000x reference)
//
#include <hip/hip_runtime.h>
#include <hip/hip_bf16.h>
#include <stdint.h>

// Problem constants (reference: N=20000, E=640000, C=D=M=128)
#define DIM 128

__device__ __forceinline__ float prelu_f(float v, float a) { return v >= 0.f ? v : a * v; }

// Order-preserving float -> uint key for atomicMax-based segment max.
__device__ __forceinline__ unsigned fkey(float f) {
    unsigned b = __float_as_uint(f);
    return (b & 0x80000000u) ? ~b : (b | 0x80000000u);
}
__device__ __forceinline__ float fdec(unsigned k) {
    return (k & 0x80000000u) ? __uint_as_float(k ^ 0x80000000u) : __uint_as_float(~k);
}

__device__ __forceinline__ unsigned short f2bf(float f) {
    unsigned u = __float_as_uint(f);
    unsigned r = (u + 0x7FFFu + ((u >> 16) & 1u)) >> 16;   // RNE
    return (unsigned short)r;
}

// ---------------------------------------------------------------------------
// K1: msg_src = x@W_src + b_src ; msg_tgt = x@W_tgt ; skip = x@W_skip
// 32 nodes / block, 256 threads. Thread computes 4 nodes x 4 cols per matrix.
// ---------------------------------------------------------------------------
__global__ __launch_bounds__(256) void node_linear(
    const float* __restrict__ x,
    const float* __restrict__ Wsrc, const float* __restrict__ bsrc,
    const float* __restrict__ Wtgt, const float* __restrict__ Wskip,
    float* __restrict__ msg_src, float* __restrict__ msg_tgt, float* __restrict__ skip)
{
    __shared__ float xs[32 * DIM];
    const int t = threadIdx.x;
    const int n0 = blockIdx.x * 32;

    const float4* xg = (const float4*)(x + (size_t)n0 * DIM);
    float4* xsv = (float4*)xs;
    for (int k = t; k < 32 * DIM / 4; k += 256) xsv[k] = xg[k];
    __syncthreads();

    const int dq = t & 31;   // column quad: cols 4*dq .. 4*dq+3
    const int nb = t >> 5;   // node group 0..7 -> nodes nb*4 .. nb*4+3

    const float* Ws[3] = {Wsrc, Wtgt, Wskip};
    float* Os[3] = {msg_src, msg_tgt, skip};

    for (int mtx = 0; mtx < 3; ++mtx) {
        const float4* W4 = (const float4*)Ws[mtx];
        float acc[4][4];
        #pragma unroll
        for (int u = 0; u < 4; ++u)
            #pragma unroll
            for (int v = 0; v < 4; ++v) acc[u][v] = 0.f;

        for (int c = 0; c < DIM; c += 4) {
            float4 w0 = W4[(c + 0) * 32 + dq];
            float4 w1 = W4[(c + 1) * 32 + dq];
            float4 w2 = W4[(c + 2) * 32 + dq];
            float4 w3 = W4[(c + 3) * 32 + dq];
            #pragma unroll
            for (int u = 0; u < 4; ++u) {
                const float4 xv = *(const float4*)(xs + (nb * 4 + u) * DIM + c);
                acc[u][0] += xv.x * w0.x; acc[u][0] += xv.y * w1.x; acc[u][0] += xv.z * w2.x; acc[u][0] += xv.w * w3.x;
                acc[u][1] += xv.x * w0.y; acc[u][1] += xv.y * w1.y; acc[u][1] += xv.z * w2.y; acc[u][1] += xv.w * w3.y;
                acc[u][2] += xv.x * w0.z; acc[u][2] += xv.y * w1.z; acc[u][2] += xv.z * w2.z; acc[u][2] += xv.w * w3.z;
                acc[u][3] += xv.x * w0.w; acc[u][3] += xv.y * w1.w; acc[u][3] += xv.z * w2.w; acc[u][3] += xv.w * w3.w;
            }
        }

        float4 bb = make_float4(0.f, 0.f, 0.f, 0.f);
        if (mtx == 0) bb = ((const float4*)bsrc)[dq];
        #pragma unroll
        for (int u = 0; u < 4; ++u) {
            const int n = n0 + nb * 4 + u;
            float4 o;
            o.x = acc[u][0] + bb.x;
            o.y = acc[u][1] + bb.y;
            o.z = acc[u][2] + bb.z;
            o.w = acc[u][3] + bb.w;
            *(float4*)(Os[mtx] + (size_t)n * DIM + 4 * dq) = o;
        }
    }
}

// ---------------------------------------------------------------------------
// K2: per-edge MLP + gate. 64 edges / block, 256 threads.
//   h = prelu(msg_src[j] + msg_tgt[i], a0)
//   h = prelu(h @ W1 + b1, a1)
//   msg = h @ W2 + b2           (stored bf16)
//   gate = msg @ Wg             -> gate[], atomicMax gmax_u[i]
// LDS stride 132 floats (16B aligned rows).
// ---------------------------------------------------------------------------
#define HSTR 132

__device__ __forceinline__ void tile_gemm_64x128(
    const float* __restrict__ hin, const float4* __restrict__ W4,
    int mq, int eb, float acc[8][4])
{
    #pragma unroll
    for (int u = 0; u < 8; ++u)
        #pragma unroll
        for (int v = 0; v < 4; ++v) acc[u][v] = 0.f;

    for (int c = 0; c < DIM; c += 4) {
        float4 w0 = W4[(c + 0) * 32 + mq];
        float4 w1 = W4[(c + 1) * 32 + mq];
        float4 w2 = W4[(c + 2) * 32 + mq];
        float4 w3 = W4[(c + 3) * 32 + mq];
        #pragma unroll
        for (int u = 0; u < 8; ++u) {
            const float4 xv = *(const float4*)(hin + (eb * 8 + u) * HSTR + c);
            acc[u][0] += xv.x * w0.x; acc[u][0] += xv.y * w1.x; acc[u][0] += xv.z * w2.x; acc[u][0] += xv.w * w3.x;
            acc[u][1] += xv.x * w0.y; acc[u][1] += xv.y * w1.y; acc[u][1] += xv.z * w2.y; acc[u][1] += xv.w * w3.y;
            acc[u][2] += xv.x * w0.z; acc[u][2] += xv.y * w1.z; acc[u][2] += xv.z * w2.z; acc[u][2] += xv.w * w3.z;
            acc[u][3] += xv.x * w0.w; acc[u][3] += xv.y * w1.w; acc[u][3] += xv.z * w2.w; acc[u][3] += xv.w * w3.w;
        }
    }
}

__global__ __launch_bounds__(256) void edge_mlp(
    const int* __restrict__ eidx, int E,
    const float* __restrict__ msg_src, const float* __restrict__ msg_tgt,
    const float* __restrict__ a0p,
    const float* __restrict__ W1, const float* __restrict__ b1,
    const float* __restrict__ a1p,
    const float* __restrict__ W2, const float* __restrict__ b2,
    const float* __restrict__ Wg,
    unsigned short* __restrict__ msgbuf,   // bf16 [E,128]
    float* __restrict__ gate, unsigned* __restrict__ gmax_u)
{
    __shared__ float h1[64 * HSTR];
    __shared__ float h2[64 * HSTR];
    __shared__ int ji[64], ii[64];

    const int t = threadIdx.x;
    const int e0 = blockIdx.x * 64;
    const float a0 = *a0p, a1 = *a1p;

    if (t < 64) {
        ji[t] = eidx[e0 + t];
        ii[t] = eidx[(size_t)E + e0 + t];
    }
    __syncthreads();

    // gather + prelu(a0): 64 rows x 32 float4
    for (int k = t; k < 64 * 32; k += 256) {
        const int e = k >> 5, q = k & 31;
        const float4 s = *(const float4*)(msg_src + (size_t)ji[e] * DIM + 4 * q);
        const float4 g = *(const float4*)(msg_tgt + (size_t)ii[e] * DIM + 4 * q);
        float4 h;
        h.x = prelu_f(s.x + g.x, a0);
        h.y = prelu_f(s.y + g.y, a0);
        h.z = prelu_f(s.z + g.z, a0);
        h.w = prelu_f(s.w + g.w, a0);
        *(float4*)(h1 + e * HSTR + 4 * q) = h;
    }
    __syncthreads();

    const int mq = t & 31;   // output col quad
    const int eb = t >> 5;   // edge group (8 edges each)
    float acc[8][4];

    // GEMM1: h2 = prelu(h1 @ W1 + b1, a1)
    tile_gemm_64x128(h1, (const float4*)W1, mq, eb, acc);
    {
        const float4 bb = ((const float4*)b1)[mq];
        #pragma unroll
        for (int u = 0; u < 8; ++u) {
            float4 o;
            o.x = prelu_f(acc[u][0] + bb.x, a1);
            o.y = prelu_f(acc[u][1] + bb.y, a1);
            o.z = prelu_f(acc[u][2] + bb.z, a1);
            o.w = prelu_f(acc[u][3] + bb.w, a1);
            *(float4*)(h2 + (eb * 8 + u) * HSTR + 4 * mq) = o;
        }
    }
    __syncthreads();

    // GEMM2: msg = h2 @ W2 + b2 ; gate = msg @ Wg
    tile_gemm_64x128(h2, (const float4*)W2, mq, eb, acc);
    {
        const float4 bb = ((const float4*)b2)[mq];
        const float4 wg = ((const float4*)Wg)[mq];
        #pragma unroll
        for (int u = 0; u < 8; ++u) {
            const int e = eb * 8 + u;
            const float m0 = acc[u][0] + bb.x;
            const float m1 = acc[u][1] + bb.y;
            const float m2 = acc[u][2] + bb.z;
            const float m3 = acc[u][3] + bb.w;

            ushort4 bs;
            bs.x = f2bf(m0); bs.y = f2bf(m1); bs.z = f2bf(m2); bs.w = f2bf(m3);
            *(ushort4*)(msgbuf + (size_t)(e0 + e) * DIM + 4 * mq) = bs;

            float p = m0 * wg.x + m1 * wg.y + m2 * wg.z + m3 * wg.w;
            p += __shfl_xor(p, 1);
            p += __shfl_xor(p, 2);
            p += __shfl_xor(p, 4);
            p += __shfl_xor(p, 8);
            p += __shfl_xor(p, 16);
            if (mq == 0) {
                gate[e0 + e] = p;
                atomicMax(gmax_u + ii[e], fkey(p));
            }
        }
    }
}

// ---------------------------------------------------------------------------
// K3: eg = exp(gate - gmax[i]); gsum[i] += eg
// ---------------------------------------------------------------------------
__global__ __launch_bounds__(256) void expsum_k(
    const int* __restrict__ eidx, int E,
    const float* __restrict__ gate, const unsigned* __restrict__ gmax_u,
    float* __restrict__ eg, float* __restrict__ gsum)
{
    const int e = blockIdx.x * 256 + threadIdx.x;
    if (e >= E) return;
    const int i = eidx[(size_t)E + e];
    const float ex = expf(gate[e] - fdec(gmax_u[i]));
    eg[e] = ex;
    atomicAdd(gsum + i, ex);
}

// ---------------------------------------------------------------------------
// K4: out_pre[i] += alpha[e] * msg[e]   (atomicAdd; 16 threads per edge)
// ---------------------------------------------------------------------------
__global__ __launch_bounds__(256) void aggregate_k(
    const int* __restrict__ eidx, int E,
    const unsigned short* __restrict__ msgbuf,
    const float* __restrict__ eg, const float* __restrict__ gsum,
    float* __restrict__ out_pre)
{
    const int t = blockIdx.x * 256 + threadIdx.x;
    const int e = t >> 4, oct = t & 15;
    if (e >= E) return;
    const int i = eidx[(size_t)E + e];
    const float alpha = eg[e] / (gsum[i] + 1e-16f);

    const uint4 mv = *(const uint4*)(msgbuf + (size_t)e * DIM + oct * 8);
    float* op = out_pre + (size_t)i * DIM + oct * 8;

    atomicAdd(op + 0, alpha * __uint_as_float(mv.x << 16));
    atomicAdd(op + 1, alpha * __uint_as_float(mv.x & 0xFFFF0000u));
    atomicAdd(op + 2, alpha * __uint_as_float(mv.y << 16));
    atomicAdd(op + 3, alpha * __uint_as_float(mv.y & 0xFFFF0000u));
    atomicAdd(op + 4, alpha * __uint_as_float(mv.z << 16));
    atomicAdd(op + 5, alpha * __uint_as_float(mv.z & 0xFFFF0000u));
    atomicAdd(op + 6, alpha * __uint_as_float(mv.w << 16));
    atomicAdd(op + 7, alpha * __uint_as_float(mv.w & 0xFFFF0000u));
}

// ---------------------------------------------------------------------------
// K5: out = LayerNorm(out_pre + skip) * gamma + beta. One wave per node.
// Safe to run in-place (out == out_pre): each thread reads its own locations
// before any write.
// ---------------------------------------------------------------------------
__global__ __launch_bounds__(256) void skip_ln_k(
    const float* __restrict__ out_pre, const float* __restrict__ skip,
    const float* __restrict__ gamma, const float* __restrict__ beta,
    float* __restrict__ out, int N)
{
    const int t = threadIdx.x;
    const int lane = t & 63, w = t >> 6;
    const int n = blockIdx.x * 4 + w;
    if (n >= N) return;

    const float* p = out_pre + (size_t)n * DIM;
    const float* s = skip + (size_t)n * DIM;
    const float v0 = p[lane] + s[lane];
    const float v1 = p[lane + 64] + s[lane + 64];

    float sum = v0 + v1;
    float sq = v0 * v0 + v1 * v1;
    #pragma unroll
    for (int m = 1; m < 64; m <<= 1) {
        sum += __shfl_xor(sum, m);
        sq  += __shfl_xor(sq, m);
    }
    const float mu = sum * (1.f / 128.f);
    const float var = sq * (1.f / 128.f) - mu * mu;
    const float rs = rsqrtf(var + 1e-5f);

    out[(size_t)n * DIM + lane]      = (v0 - mu) * rs * gamma[lane] + beta[lane];
    out[(size_t)n * DIM + lane + 64] = (v1 - mu) * rs * gamma[lane + 64] + beta[lane + 64];
}

// ---------------------------------------------------------------------------
extern "C" void kernel_launch(void* const* d_in, const int* in_sizes, int n_in,
                              void* d_out, int out_size, void* d_ws, size_t ws_size,
                              hipStream_t stream)
{
    const float* x     = (const float*)d_in[0];
    const int*   eidx  = (const int*)d_in[1];        // harness: integer -> int32
    const float* Wsrc  = (const float*)d_in[2];
    const float* bsrc  = (const float*)d_in[3];
    const float* Wtgt  = (const float*)d_in[4];
    const float* Wskip = (const float*)d_in[5];
    const float* a0    = (const float*)d_in[6];
    const float* W1    = (const float*)d_in[7];
    const float* b1    = (const float*)d_in[8];
    const float* a1    = (const float*)d_in[9];
    const float* W2    = (const float*)d_in[10];
    const float* b2    = (const float*)d_in[11];
    const float* Wg    = (const float*)d_in[12];
    const float* gamma = (const float*)d_in[13];
    const float* beta  = (const float*)d_in[14];

    const int N = in_sizes[0] / DIM;      // 20000
    const int E = in_sizes[1] / 2;        // 640000
    float* out = (float*)d_out;

    // Workspace carve-up (256B aligned). d_out doubles as the out_pre
    // accumulator (skip_ln_k is in-place safe).
    char* ws = (char*)d_ws;
    size_t off = 0;
    auto alloc = [&](size_t bytes) -> void* {
        void* p = ws + off;
        off += (bytes + 255) & ~(size_t)255;
        return p;
    };
    float*          msg_src = (float*)alloc((size_t)N * DIM * 4);
    float*          msg_tgt = (float*)alloc((size_t)N * DIM * 4);
    float*          skip    = (float*)alloc((size_t)N * DIM * 4);
    float*          gate    = (float*)alloc((size_t)E * 4);
    float*          eg      = (float*)alloc((size_t)E * 4);
    float*          gsum    = (float*)alloc((size_t)N * 4);   // zero region start
    unsigned*       gmax_u  = (unsigned*)alloc((size_t)N * 4);
    unsigned short* msgbuf  = (unsigned short*)alloc((size_t)E * DIM * 2);
    float*          out_pre = out;
    (void)ws_size; (void)n_in; (void)out_size;

    // Zero gsum + gmax (contiguous; gmax key 0 decodes below any real gate)
    // and out_pre (= d_out, poisoned by harness).
    hipMemsetAsync(gsum, 0, (size_t)N * 8, stream);
    hipMemsetAsync(out_pre, 0, (size_t)N * DIM * 4, stream);

    node_linear<<<N / 32, 256, 0, stream>>>(x, Wsrc, bsrc, Wtgt, Wskip, msg_src, msg_tgt, skip);

    edge_mlp<<<E / 64, 256, 0, stream>>>(eidx, E, msg_src, msg_tgt, a0, W1, b1, a1, W2, b2, Wg,
                                         msgbuf, gate, gmax_u);

    expsum_k<<<(E + 255) / 256, 256, 0, stream>>>(eidx, E, gate, gmax_u, eg, gsum);

    aggregate_k<<<(E * 16 + 255) / 256, 256, 0, stream>>>(eidx, E, msgbuf, eg, gsum, out_pre);

    skip_ln_k<<<(N + 3) / 4, 256, 0, stream>>>(out_pre, skip, gamma, beta, out, N);
}

// Round 3
// 884.391 us; speedup vs baseline: 3.4842x; 3.4842x over previous
//
#include <hip/hip_runtime.h>
#include <hip/hip_bf16.h>
#include <stdint.h>

// Problem constants (reference: N=20000, E=640000, C=D=M=128)
#define DIM 128

__device__ __forceinline__ float prelu_f(float v, float a) { return v >= 0.f ? v : a * v; }

__device__ __forceinline__ unsigned short f2bf(float f) {
    unsigned u = __float_as_uint(f);
    unsigned r = (u + 0x7FFFu + ((u >> 16) & 1u)) >> 16;   // RNE
    return (unsigned short)r;
}
__device__ __forceinline__ float bf_lo(unsigned u) { return __uint_as_float(u << 16); }
__device__ __forceinline__ float bf_hi(unsigned u) { return __uint_as_float(u & 0xFFFF0000u); }

// ---------------------------------------------------------------------------
// K1: msg_src = x@W_src + b_src ; msg_tgt = x@W_tgt ; skip = x@W_skip
// 32 nodes / block, 256 threads. Thread computes 4 nodes x 4 cols per matrix.
// ---------------------------------------------------------------------------
__global__ __launch_bounds__(256) void node_linear(
    const float* __restrict__ x,
    const float* __restrict__ Wsrc, const float* __restrict__ bsrc,
    const float* __restrict__ Wtgt, const float* __restrict__ Wskip,
    float* __restrict__ msg_src, float* __restrict__ msg_tgt, float* __restrict__ skip)
{
    __shared__ float xs[32 * DIM];
    const int t = threadIdx.x;
    const int n0 = blockIdx.x * 32;

    const float4* xg = (const float4*)(x + (size_t)n0 * DIM);
    float4* xsv = (float4*)xs;
    for (int k = t; k < 32 * DIM / 4; k += 256) xsv[k] = xg[k];
    __syncthreads();

    const int dq = t & 31;   // column quad: cols 4*dq .. 4*dq+3
    const int nb = t >> 5;   // node group 0..7 -> nodes nb*4 .. nb*4+3

    const float* Ws[3] = {Wsrc, Wtgt, Wskip};
    float* Os[3] = {msg_src, msg_tgt, skip};

    for (int mtx = 0; mtx < 3; ++mtx) {
        const float4* W4 = (const float4*)Ws[mtx];
        float acc[4][4];
        #pragma unroll
        for (int u = 0; u < 4; ++u)
            #pragma unroll
            for (int v = 0; v < 4; ++v) acc[u][v] = 0.f;

        for (int c = 0; c < DIM; c += 4) {
            float4 w0 = W4[(c + 0) * 32 + dq];
            float4 w1 = W4[(c + 1) * 32 + dq];
            float4 w2 = W4[(c + 2) * 32 + dq];
            float4 w3 = W4[(c + 3) * 32 + dq];
            #pragma unroll
            for (int u = 0; u < 4; ++u) {
                const float4 xv = *(const float4*)(xs + (nb * 4 + u) * DIM + c);
                acc[u][0] += xv.x * w0.x; acc[u][0] += xv.y * w1.x; acc[u][0] += xv.z * w2.x; acc[u][0] += xv.w * w3.x;
                acc[u][1] += xv.x * w0.y; acc[u][1] += xv.y * w1.y; acc[u][1] += xv.z * w2.y; acc[u][1] += xv.w * w3.y;
                acc[u][2] += xv.x * w0.z; acc[u][2] += xv.y * w1.z; acc[u][2] += xv.z * w2.z; acc[u][2] += xv.w * w3.z;
                acc[u][3] += xv.x * w0.w; acc[u][3] += xv.y * w1.w; acc[u][3] += xv.z * w2.w; acc[u][3] += xv.w * w3.w;
            }
        }

        float4 bb = make_float4(0.f, 0.f, 0.f, 0.f);
        if (mtx == 0) bb = ((const float4*)bsrc)[dq];
        #pragma unroll
        for (int u = 0; u < 4; ++u) {
            const int n = n0 + nb * 4 + u;
            float4 o;
            o.x = acc[u][0] + bb.x;
            o.y = acc[u][1] + bb.y;
            o.z = acc[u][2] + bb.z;
            o.w = acc[u][3] + bb.w;
            *(float4*)(Os[mtx] + (size_t)n * DIM + 4 * dq) = o;
        }
    }
}

// ---------------------------------------------------------------------------
// CSR build: histogram -> single-block scan -> scatter
// ---------------------------------------------------------------------------
__global__ __launch_bounds__(256) void hist_k(const int* __restrict__ eidx, int E,
                                              int* __restrict__ deg)
{
    const int e = blockIdx.x * 256 + threadIdx.x;
    if (e < E) atomicAdd(deg + eidx[(size_t)E + e], 1);
}

__global__ __launch_bounds__(256) void scan_k(const int* __restrict__ deg,
                                              int* __restrict__ rowptr,
                                              int* __restrict__ cursor, int N)
{
    __shared__ int part[256];
    const int t = threadIdx.x;
    const int chunk = (N + 255) / 256;
    const int lo = t * chunk;
    const int hi = min(lo + chunk, N);

    int s = 0;
    for (int k = lo; k < hi; ++k) s += deg[k];
    part[t] = s;
    __syncthreads();

    // Hillis-Steele inclusive scan in LDS
    for (int off = 1; off < 256; off <<= 1) {
        int u = (t >= off) ? part[t - off] : 0;
        __syncthreads();
        part[t] += u;
        __syncthreads();
    }

    int run = part[t] - s;   // exclusive prefix for this thread's chunk
    for (int k = lo; k < hi; ++k) {
        rowptr[k] = run;
        cursor[k] = run;
        run += deg[k];
    }
    if (t == 255) rowptr[N] = part[255];   // total
}

__global__ __launch_bounds__(256) void scatter_k(const int* __restrict__ eidx, int E,
                                                 int* __restrict__ cursor,
                                                 int* __restrict__ perm)
{
    const int e = blockIdx.x * 256 + threadIdx.x;
    if (e < E) {
        const int i = eidx[(size_t)E + e];
        const int p = atomicAdd(cursor + i, 1);
        perm[p] = e;
    }
}

// ---------------------------------------------------------------------------
// K2: per-edge MLP + gate. 64 edges / block, 256 threads.
//   h = prelu(msg_src[j] + msg_tgt[i], a0)
//   h = prelu(h @ W1 + b1, a1)
//   msg = h @ W2 + b2           (stored bf16)
//   gate = msg @ Wg             -> gate[]
// ---------------------------------------------------------------------------
#define HSTR 132

__device__ __forceinline__ void tile_gemm_64x128(
    const float* __restrict__ hin, const float4* __restrict__ W4,
    int mq, int eb, float acc[8][4])
{
    #pragma unroll
    for (int u = 0; u < 8; ++u)
        #pragma unroll
        for (int v = 0; v < 4; ++v) acc[u][v] = 0.f;

    for (int c = 0; c < DIM; c += 4) {
        float4 w0 = W4[(c + 0) * 32 + mq];
        float4 w1 = W4[(c + 1) * 32 + mq];
        float4 w2 = W4[(c + 2) * 32 + mq];
        float4 w3 = W4[(c + 3) * 32 + mq];
        #pragma unroll
        for (int u = 0; u < 8; ++u) {
            const float4 xv = *(const float4*)(hin + (eb * 8 + u) * HSTR + c);
            acc[u][0] += xv.x * w0.x; acc[u][0] += xv.y * w1.x; acc[u][0] += xv.z * w2.x; acc[u][0] += xv.w * w3.x;
            acc[u][1] += xv.x * w0.y; acc[u][1] += xv.y * w1.y; acc[u][1] += xv.z * w2.y; acc[u][1] += xv.w * w3.y;
            acc[u][2] += xv.x * w0.z; acc[u][2] += xv.y * w1.z; acc[u][2] += xv.z * w2.z; acc[u][2] += xv.w * w3.z;
            acc[u][3] += xv.x * w0.w; acc[u][3] += xv.y * w1.w; acc[u][3] += xv.z * w2.w; acc[u][3] += xv.w * w3.w;
        }
    }
}

__global__ __launch_bounds__(256) void edge_mlp(
    const int* __restrict__ eidx, int E,
    const float* __restrict__ msg_src, const float* __restrict__ msg_tgt,
    const float* __restrict__ a0p,
    const float* __restrict__ W1, const float* __restrict__ b1,
    const float* __restrict__ a1p,
    const float* __restrict__ W2, const float* __restrict__ b2,
    const float* __restrict__ Wg,
    unsigned short* __restrict__ msgbuf,   // bf16 [E,128]
    float* __restrict__ gate)
{
    __shared__ float h1[64 * HSTR];
    __shared__ float h2[64 * HSTR];
    __shared__ int ji[64], ii[64];

    const int t = threadIdx.x;
    const int e0 = blockIdx.x * 64;
    const float a0 = *a0p, a1 = *a1p;

    if (t < 64) {
        ji[t] = eidx[e0 + t];
        ii[t] = eidx[(size_t)E + e0 + t];
    }
    __syncthreads();

    // gather + prelu(a0): 64 rows x 32 float4
    for (int k = t; k < 64 * 32; k += 256) {
        const int e = k >> 5, q = k & 31;
        const float4 s = *(const float4*)(msg_src + (size_t)ji[e] * DIM + 4 * q);
        const float4 g = *(const float4*)(msg_tgt + (size_t)ii[e] * DIM + 4 * q);
        float4 h;
        h.x = prelu_f(s.x + g.x, a0);
        h.y = prelu_f(s.y + g.y, a0);
        h.z = prelu_f(s.z + g.z, a0);
        h.w = prelu_f(s.w + g.w, a0);
        *(float4*)(h1 + e * HSTR + 4 * q) = h;
    }
    __syncthreads();

    const int mq = t & 31;   // output col quad
    const int eb = t >> 5;   // edge group (8 edges each)
    float acc[8][4];

    // GEMM1: h2 = prelu(h1 @ W1 + b1, a1)
    tile_gemm_64x128(h1, (const float4*)W1, mq, eb, acc);
    {
        const float4 bb = ((const float4*)b1)[mq];
        #pragma unroll
        for (int u = 0; u < 8; ++u) {
            float4 o;
            o.x = prelu_f(acc[u][0] + bb.x, a1);
            o.y = prelu_f(acc[u][1] + bb.y, a1);
            o.z = prelu_f(acc[u][2] + bb.z, a1);
            o.w = prelu_f(acc[u][3] + bb.w, a1);
            *(float4*)(h2 + (eb * 8 + u) * HSTR + 4 * mq) = o;
        }
    }
    __syncthreads();

    // GEMM2: msg = h2 @ W2 + b2 ; gate = msg @ Wg
    tile_gemm_64x128(h2, (const float4*)W2, mq, eb, acc);
    {
        const float4 bb = ((const float4*)b2)[mq];
        const float4 wg = ((const float4*)Wg)[mq];
        #pragma unroll
        for (int u = 0; u < 8; ++u) {
            const int e = eb * 8 + u;
            const float m0 = acc[u][0] + bb.x;
            const float m1 = acc[u][1] + bb.y;
            const float m2 = acc[u][2] + bb.z;
            const float m3 = acc[u][3] + bb.w;

            ushort4 bs;
            bs.x = f2bf(m0); bs.y = f2bf(m1); bs.z = f2bf(m2); bs.w = f2bf(m3);
            *(ushort4*)(msgbuf + (size_t)(e0 + e) * DIM + 4 * mq) = bs;

            float p = m0 * wg.x + m1 * wg.y + m2 * wg.z + m3 * wg.w;
            p += __shfl_xor(p, 1);
            p += __shfl_xor(p, 2);
            p += __shfl_xor(p, 4);
            p += __shfl_xor(p, 8);
            p += __shfl_xor(p, 16);
            if (mq == 0) gate[e0 + e] = p;
        }
    }
}

// ---------------------------------------------------------------------------
// K4: wave-per-node softmax + aggregate + skip + LayerNorm (no atomics).
// 4 waves (nodes) per 256-thread block.
//   pass1: m = max gate over node's edges (wave reduce)
//   pass2: s = sum exp(gate-m)            (wave reduce)
//   pass3: 4 groups of 16 lanes, each group one edge at a time;
//          lane holds 8 dims (16B bf16 load). Cross-group reduce via shfl.
//   epilogue: + skip, LayerNorm, write out.
// ---------------------------------------------------------------------------
__global__ __launch_bounds__(256) void aggregate_ln_k(
    const int* __restrict__ rowptr, const int* __restrict__ perm,
    const float* __restrict__ gate, const unsigned short* __restrict__ msgbuf,
    const float* __restrict__ skip,
    const float* __restrict__ gamma, const float* __restrict__ beta,
    float* __restrict__ out, int N)
{
    const int n = blockIdx.x * 4 + (threadIdx.x >> 6);
    const int lane = threadIdx.x & 63;
    if (n >= N) return;

    const int base = rowptr[n];
    const int deg = rowptr[n + 1] - base;

    // pass 1: segment max
    float m = -INFINITY;
    for (int k = lane; k < deg; k += 64) m = fmaxf(m, gate[perm[base + k]]);
    #pragma unroll
    for (int off = 1; off < 64; off <<= 1) m = fmaxf(m, __shfl_xor(m, off));

    // pass 2: segment sum of exp
    float s = 0.f;
    for (int k = lane; k < deg; k += 64) s += __expf(gate[perm[base + k]] - m);
    #pragma unroll
    for (int off = 1; off < 64; off <<= 1) s += __shfl_xor(s, off);
    const float inv = 1.f / (s + 1e-16f);

    // pass 3: weighted accumulation. group = 16 lanes covering 128 dims.
    const int grp = lane >> 4, sub = lane & 15;
    float acc[8] = {0.f, 0.f, 0.f, 0.f, 0.f, 0.f, 0.f, 0.f};
    for (int k = grp; k < deg; k += 4) {
        const int e = perm[base + k];                     // uniform across group
        const float w = __expf(gate[e] - m) * inv;
        const uint4 mv = *(const uint4*)(msgbuf + (size_t)e * DIM + sub * 8);
        acc[0] += w * bf_lo(mv.x); acc[1] += w * bf_hi(mv.x);
        acc[2] += w * bf_lo(mv.y); acc[3] += w * bf_hi(mv.y);
        acc[4] += w * bf_lo(mv.z); acc[5] += w * bf_hi(mv.z);
        acc[6] += w * bf_lo(mv.w); acc[7] += w * bf_hi(mv.w);
    }
    #pragma unroll
    for (int j = 0; j < 8; ++j) {
        acc[j] += __shfl_xor(acc[j], 16);
        acc[j] += __shfl_xor(acc[j], 32);
    }

    // epilogue: + skip, LayerNorm over 128 dims (16 lanes x 8 dims, replicated 4x)
    const float4 s0 = *(const float4*)(skip + (size_t)n * DIM + sub * 8);
    const float4 s1 = *(const float4*)(skip + (size_t)n * DIM + sub * 8 + 4);
    float v[8];
    v[0] = acc[0] + s0.x; v[1] = acc[1] + s0.y; v[2] = acc[2] + s0.z; v[3] = acc[3] + s0.w;
    v[4] = acc[4] + s1.x; v[5] = acc[5] + s1.y; v[6] = acc[6] + s1.z; v[7] = acc[7] + s1.w;

    float sum = 0.f, sq = 0.f;
    #pragma unroll
    for (int j = 0; j < 8; ++j) { sum += v[j]; sq += v[j] * v[j]; }
    #pragma unroll
    for (int off = 1; off < 16; off <<= 1) {   // reduce within 16-lane group
        sum += __shfl_xor(sum, off);
        sq  += __shfl_xor(sq, off);
    }
    const float mu = sum * (1.f / 128.f);
    const float var = sq * (1.f / 128.f) - mu * mu;
    const float rs = rsqrtf(var + 1e-5f);

    if (grp == 0) {
        const float4 g0 = *(const float4*)(gamma + sub * 8);
        const float4 g1 = *(const float4*)(gamma + sub * 8 + 4);
        const float4 be0 = *(const float4*)(beta + sub * 8);
        const float4 be1 = *(const float4*)(beta + sub * 8 + 4);
        float4 o0, o1;
        o0.x = (v[0] - mu) * rs * g0.x + be0.x;
        o0.y = (v[1] - mu) * rs * g0.y + be0.y;
        o0.z = (v[2] - mu) * rs * g0.z + be0.z;
        o0.w = (v[3] - mu) * rs * g0.w + be0.w;
        o1.x = (v[4] - mu) * rs * g1.x + be1.x;
        o1.y = (v[5] - mu) * rs * g1.y + be1.y;
        o1.z = (v[6] - mu) * rs * g1.z + be1.z;
        o1.w = (v[7] - mu) * rs * g1.w + be1.w;
        *(float4*)(out + (size_t)n * DIM + sub * 8) = o0;
        *(float4*)(out + (size_t)n * DIM + sub * 8 + 4) = o1;
    }
}

// ---------------------------------------------------------------------------
extern "C" void kernel_launch(void* const* d_in, const int* in_sizes, int n_in,
                              void* d_out, int out_size, void* d_ws, size_t ws_size,
                              hipStream_t stream)
{
    const float* x     = (const float*)d_in[0];
    const int*   eidx  = (const int*)d_in[1];        // harness: integer -> int32
    const float* Wsrc  = (const float*)d_in[2];
    const float* bsrc  = (const float*)d_in[3];
    const float* Wtgt  = (const float*)d_in[4];
    const float* Wskip = (const float*)d_in[5];
    const float* a0    = (const float*)d_in[6];
    const float* W1    = (const float*)d_in[7];
    const float* b1    = (const float*)d_in[8];
    const float* a1    = (const float*)d_in[9];
    const float* W2    = (const float*)d_in[10];
    const float* b2    = (const float*)d_in[11];
    const float* Wg    = (const float*)d_in[12];
    const float* gamma = (const float*)d_in[13];
    const float* beta  = (const float*)d_in[14];

    const int N = in_sizes[0] / DIM;      // 20000
    const int E = in_sizes[1] / 2;        // 640000
    float* out = (float*)d_out;

    // Workspace carve-up (256B aligned).
    char* ws = (char*)d_ws;
    size_t off = 0;
    auto alloc = [&](size_t bytes) -> void* {
        void* p = ws + off;
        off += (bytes + 255) & ~(size_t)255;
        return p;
    };
    float*          msg_src = (float*)alloc((size_t)N * DIM * 4);
    float*          msg_tgt = (float*)alloc((size_t)N * DIM * 4);
    float*          skip    = (float*)alloc((size_t)N * DIM * 4);
    float*          gate    = (float*)alloc((size_t)E * 4);
    int*            deg     = (int*)alloc((size_t)N * 4);
    int*            rowptr  = (int*)alloc((size_t)(N + 1) * 4);
    int*            cursor  = (int*)alloc((size_t)N * 4);
    int*            perm    = (int*)alloc((size_t)E * 4);
    unsigned short* msgbuf  = (unsigned short*)alloc((size_t)E * DIM * 2);
    (void)ws_size; (void)n_in; (void)out_size;

    hipMemsetAsync(deg, 0, (size_t)N * 4, stream);

    hist_k<<<(E + 255) / 256, 256, 0, stream>>>(eidx, E, deg);
    scan_k<<<1, 256, 0, stream>>>(deg, rowptr, cursor, N);
    scatter_k<<<(E + 255) / 256, 256, 0, stream>>>(eidx, E, cursor, perm);

    node_linear<<<N / 32, 256, 0, stream>>>(x, Wsrc, bsrc, Wtgt, Wskip, msg_src, msg_tgt, skip);

    edge_mlp<<<E / 64, 256, 0, stream>>>(eidx, E, msg_src, msg_tgt, a0, W1, b1, a1, W2, b2, Wg,
                                         msgbuf, gate);

    aggregate_ln_k<<<(N + 3) / 4, 256, 0, stream>>>(rowptr, perm, gate, msgbuf, skip,
                                                    gamma, beta, out, N);
}

// Round 4
// 463.064 us; speedup vs baseline: 6.6544x; 1.9099x over previous
//
#include <hip/hip_runtime.h>
#include <hip/hip_bf16.h>
#include <stdint.h>

// Problem constants (reference: N=20000, E=640000, C=D=M=128)
#define DIM 128
#define HSTR 136   // padded LDS row stride in bf16 elems (272 B; 2-way bank alias = free)

using bfrag = __attribute__((ext_vector_type(8))) short;   // 8 bf16 (4 VGPRs)
using f32x4 = __attribute__((ext_vector_type(4))) float;   // MFMA C/D

__device__ __forceinline__ float prelu_f(float v, float a) { return v >= 0.f ? v : a * v; }

__device__ __forceinline__ unsigned short f2bf(float f) {
    unsigned u = __float_as_uint(f);
    unsigned r = (u + 0x7FFFu + ((u >> 16) & 1u)) >> 16;   // RNE
    return (unsigned short)r;
}
__device__ __forceinline__ float bf_lo(unsigned u) { return __uint_as_float(u << 16); }
__device__ __forceinline__ float bf_hi(unsigned u) { return __uint_as_float(u & 0xFFFF0000u); }

// ---------------------------------------------------------------------------
// K1: msg_src = x@W_src + b_src ; msg_tgt = x@W_tgt ; skip = x@W_skip
// ---------------------------------------------------------------------------
__global__ __launch_bounds__(256) void node_linear(
    const float* __restrict__ x,
    const float* __restrict__ Wsrc, const float* __restrict__ bsrc,
    const float* __restrict__ Wtgt, const float* __restrict__ Wskip,
    float* __restrict__ msg_src, float* __restrict__ msg_tgt, float* __restrict__ skip)
{
    __shared__ float xs[32 * DIM];
    const int t = threadIdx.x;
    const int n0 = blockIdx.x * 32;

    const float4* xg = (const float4*)(x + (size_t)n0 * DIM);
    float4* xsv = (float4*)xs;
    for (int k = t; k < 32 * DIM / 4; k += 256) xsv[k] = xg[k];
    __syncthreads();

    const int dq = t & 31;
    const int nb = t >> 5;

    const float* Ws[3] = {Wsrc, Wtgt, Wskip};
    float* Os[3] = {msg_src, msg_tgt, skip};

    for (int mtx = 0; mtx < 3; ++mtx) {
        const float4* W4 = (const float4*)Ws[mtx];
        float acc[4][4];
        #pragma unroll
        for (int u = 0; u < 4; ++u)
            #pragma unroll
            for (int v = 0; v < 4; ++v) acc[u][v] = 0.f;

        for (int c = 0; c < DIM; c += 4) {
            float4 w0 = W4[(c + 0) * 32 + dq];
            float4 w1 = W4[(c + 1) * 32 + dq];
            float4 w2 = W4[(c + 2) * 32 + dq];
            float4 w3 = W4[(c + 3) * 32 + dq];
            #pragma unroll
            for (int u = 0; u < 4; ++u) {
                const float4 xv = *(const float4*)(xs + (nb * 4 + u) * DIM + c);
                acc[u][0] += xv.x * w0.x; acc[u][0] += xv.y * w1.x; acc[u][0] += xv.z * w2.x; acc[u][0] += xv.w * w3.x;
                acc[u][1] += xv.x * w0.y; acc[u][1] += xv.y * w1.y; acc[u][1] += xv.z * w2.y; acc[u][1] += xv.w * w3.y;
                acc[u][2] += xv.x * w0.z; acc[u][2] += xv.y * w1.z; acc[u][2] += xv.z * w2.z; acc[u][2] += xv.w * w3.z;
                acc[u][3] += xv.x * w0.w; acc[u][3] += xv.y * w1.w; acc[u][3] += xv.z * w2.w; acc[u][3] += xv.w * w3.w;
            }
        }

        float4 bb = make_float4(0.f, 0.f, 0.f, 0.f);
        if (mtx == 0) bb = ((const float4*)bsrc)[dq];
        #pragma unroll
        for (int u = 0; u < 4; ++u) {
            const int n = n0 + nb * 4 + u;
            float4 o;
            o.x = acc[u][0] + bb.x;
            o.y = acc[u][1] + bb.y;
            o.z = acc[u][2] + bb.z;
            o.w = acc[u][3] + bb.w;
            *(float4*)(Os[mtx] + (size_t)n * DIM + 4 * dq) = o;
        }
    }
}

// ---------------------------------------------------------------------------
// Weight prep: Wt[n][k] = bf16(W[k][n])  for W1, W2  (B-fragment friendly)
// ---------------------------------------------------------------------------
__global__ __launch_bounds__(256) void prep_w_k(
    const float* __restrict__ W1, const float* __restrict__ W2,
    unsigned short* __restrict__ W1t, unsigned short* __restrict__ W2t)
{
    const int idx = blockIdx.x * 256 + threadIdx.x;
    if (idx >= 2 * DIM * DIM) return;
    const float* W = (idx < DIM * DIM) ? W1 : W2;
    unsigned short* O = (idx < DIM * DIM) ? W1t : W2t;
    const int r = idx & (DIM * DIM - 1);
    const int n = r >> 7, k = r & 127;
    O[r] = f2bf(W[k * DIM + n]);
}

// ---------------------------------------------------------------------------
// CSR build: histogram -> single-block scan -> scatter
// ---------------------------------------------------------------------------
__global__ __launch_bounds__(256) void hist_k(const int* __restrict__ eidx, int E,
                                              int* __restrict__ deg)
{
    const int e = blockIdx.x * 256 + threadIdx.x;
    if (e < E) atomicAdd(deg + eidx[(size_t)E + e], 1);
}

__global__ __launch_bounds__(256) void scan_k(const int* __restrict__ deg,
                                              int* __restrict__ rowptr,
                                              int* __restrict__ cursor, int N)
{
    __shared__ int part[256];
    const int t = threadIdx.x;
    const int chunk = (N + 255) / 256;
    const int lo = t * chunk;
    const int hi = min(lo + chunk, N);

    int s = 0;
    for (int k = lo; k < hi; ++k) s += deg[k];
    part[t] = s;
    __syncthreads();

    for (int off = 1; off < 256; off <<= 1) {
        int u = (t >= off) ? part[t - off] : 0;
        __syncthreads();
        part[t] += u;
        __syncthreads();
    }

    int run = part[t] - s;
    for (int k = lo; k < hi; ++k) {
        rowptr[k] = run;
        cursor[k] = run;
        run += deg[k];
    }
    if (t == 255) rowptr[N] = part[255];
}

__global__ __launch_bounds__(256) void scatter_k(const int* __restrict__ eidx, int E,
                                                 int* __restrict__ cursor,
                                                 int* __restrict__ perm)
{
    const int e = blockIdx.x * 256 + threadIdx.x;
    if (e < E) {
        const int i = eidx[(size_t)E + e];
        const int p = atomicAdd(cursor + i, 1);
        perm[p] = e;
    }
}

// ---------------------------------------------------------------------------
// K2: per-edge MLP + gate via bf16 MFMA. 64 edges/block, 4 waves.
// Wave w owns N-slice [w*32, w*32+32); B-frags of W1,W2 held in registers.
// A-frag layout: lane holds A[m=lane&15][k=quad*8+j]; D: col=lane&15,
// row=quad*4+reg (m89/m91-verified mappings).
// ---------------------------------------------------------------------------
__global__ __launch_bounds__(256) void edge_mlp_mfma(
    const int* __restrict__ eidx, int E,
    const float* __restrict__ msg_src, const float* __restrict__ msg_tgt,
    const float* __restrict__ a0p,
    const unsigned short* __restrict__ W1t, const float* __restrict__ b1,
    const float* __restrict__ a1p,
    const unsigned short* __restrict__ W2t, const float* __restrict__ b2,
    const float* __restrict__ Wg,
    unsigned short* __restrict__ msgbuf,   // bf16 [E,128]
    float* __restrict__ gate)
{
    __shared__ unsigned short h1[64 * HSTR];
    __shared__ unsigned short h2[64 * HSTR];
    __shared__ int ji[64], ii[64];
    __shared__ float gate_part[4][64];

    const int t = threadIdx.x;
    const int e0 = blockIdx.x * 64;
    const float a0 = *a0p, a1 = *a1p;
    const int w = t >> 6, lane = t & 63, col = lane & 15, quad = lane >> 4;

    // B-fragments for this wave's 32-column slice: registers, loaded once.
    bfrag bw1[2][4], bw2[2][4];
    float b1v[2], b2v[2], wgv[2];
    #pragma unroll
    for (int nt = 0; nt < 2; ++nt) {
        const int n = w * 32 + nt * 16 + col;
        #pragma unroll
        for (int ks = 0; ks < 4; ++ks) {
            const int k0 = ks * 32 + quad * 8;
            bw1[nt][ks] = *(const bfrag*)(W1t + n * DIM + k0);
            bw2[nt][ks] = *(const bfrag*)(W2t + n * DIM + k0);
        }
        b1v[nt] = b1[n];
        b2v[nt] = b2[n];
        wgv[nt] = Wg[n];
    }

    if (t < 64) {
        ji[t] = eidx[e0 + t];
        ii[t] = eidx[(size_t)E + e0 + t];
    }
    __syncthreads();

    // gather + prelu(a0) + cvt -> h1 (bf16)
    for (int k = t; k < 64 * 32; k += 256) {
        const int e = k >> 5, q = k & 31;
        const float4 s = *(const float4*)(msg_src + (size_t)ji[e] * DIM + 4 * q);
        const float4 g = *(const float4*)(msg_tgt + (size_t)ii[e] * DIM + 4 * q);
        ushort4 hv;
        hv.x = f2bf(prelu_f(s.x + g.x, a0));
        hv.y = f2bf(prelu_f(s.y + g.y, a0));
        hv.z = f2bf(prelu_f(s.z + g.z, a0));
        hv.w = f2bf(prelu_f(s.w + g.w, a0));
        *(ushort4*)(h1 + e * HSTR + 4 * q) = hv;
    }
    __syncthreads();

    // GEMM1: h2 = prelu(h1 @ W1 + b1, a1)
    {
        f32x4 acc[4][2];
        #pragma unroll
        for (int mt = 0; mt < 4; ++mt)
            #pragma unroll
            for (int nt = 0; nt < 2; ++nt)
                acc[mt][nt] = f32x4{0.f, 0.f, 0.f, 0.f};

        #pragma unroll
        for (int mt = 0; mt < 4; ++mt) {
            bfrag af[4];
            #pragma unroll
            for (int ks = 0; ks < 4; ++ks)
                af[ks] = *(const bfrag*)(h1 + (mt * 16 + col) * HSTR + ks * 32 + quad * 8);
            #pragma unroll
            for (int nt = 0; nt < 2; ++nt)
                #pragma unroll
                for (int ks = 0; ks < 4; ++ks)
                    acc[mt][nt] = __builtin_amdgcn_mfma_f32_16x16x32_bf16(
                        af[ks], bw1[nt][ks], acc[mt][nt], 0, 0, 0);
        }

        #pragma unroll
        for (int mt = 0; mt < 4; ++mt)
            #pragma unroll
            for (int nt = 0; nt < 2; ++nt) {
                const int n = w * 32 + nt * 16 + col;
                #pragma unroll
                for (int r = 0; r < 4; ++r) {
                    const float v = prelu_f(acc[mt][nt][r] + b1v[nt], a1);
                    h2[(mt * 16 + quad * 4 + r) * HSTR + n] = f2bf(v);
                }
            }
    }
    __syncthreads();

    // GEMM2: msg = h2 @ W2 + b2 ; gate = msg @ Wg
    {
        f32x4 acc[4][2];
        #pragma unroll
        for (int mt = 0; mt < 4; ++mt)
            #pragma unroll
            for (int nt = 0; nt < 2; ++nt)
                acc[mt][nt] = f32x4{0.f, 0.f, 0.f, 0.f};

        #pragma unroll
        for (int mt = 0; mt < 4; ++mt) {
            bfrag af[4];
            #pragma unroll
            for (int ks = 0; ks < 4; ++ks)
                af[ks] = *(const bfrag*)(h2 + (mt * 16 + col) * HSTR + ks * 32 + quad * 8);
            #pragma unroll
            for (int nt = 0; nt < 2; ++nt)
                #pragma unroll
                for (int ks = 0; ks < 4; ++ks)
                    acc[mt][nt] = __builtin_amdgcn_mfma_f32_16x16x32_bf16(
                        af[ks], bw2[nt][ks], acc[mt][nt], 0, 0, 0);
        }

        #pragma unroll
        for (int mt = 0; mt < 4; ++mt) {
            #pragma unroll
            for (int r = 0; r < 4; ++r) {
                const int row = mt * 16 + quad * 4 + r;
                const float m0 = acc[mt][0][r] + b2v[0];
                const float m1 = acc[mt][1][r] + b2v[1];
                msgbuf[(size_t)(e0 + row) * DIM + w * 32 + col]      = f2bf(m0);
                msgbuf[(size_t)(e0 + row) * DIM + w * 32 + 16 + col] = f2bf(m1);
                float g = m0 * wgv[0] + m1 * wgv[1];
                g += __shfl_xor(g, 1);
                g += __shfl_xor(g, 2);
                g += __shfl_xor(g, 4);
                g += __shfl_xor(g, 8);
                if (col == 0) gate_part[w][row] = g;
            }
        }
    }
    __syncthreads();

    if (t < 64)
        gate[e0 + t] = gate_part[0][t] + gate_part[1][t] + gate_part[2][t] + gate_part[3][t];
}

// ---------------------------------------------------------------------------
// K4: wave-per-node softmax + aggregate + skip + LayerNorm (no atomics).
// ---------------------------------------------------------------------------
__global__ __launch_bounds__(256) void aggregate_ln_k(
    const int* __restrict__ rowptr, const int* __restrict__ perm,
    const float* __restrict__ gate, const unsigned short* __restrict__ msgbuf,
    const float* __restrict__ skip,
    const float* __restrict__ gamma, const float* __restrict__ beta,
    float* __restrict__ out, int N)
{
    const int n = blockIdx.x * 4 + (threadIdx.x >> 6);
    const int lane = threadIdx.x & 63;
    if (n >= N) return;

    const int base = rowptr[n];
    const int deg = rowptr[n + 1] - base;

    float m = -INFINITY;
    for (int k = lane; k < deg; k += 64) m = fmaxf(m, gate[perm[base + k]]);
    #pragma unroll
    for (int off = 1; off < 64; off <<= 1) m = fmaxf(m, __shfl_xor(m, off));

    float s = 0.f;
    for (int k = lane; k < deg; k += 64) s += __expf(gate[perm[base + k]] - m);
    #pragma unroll
    for (int off = 1; off < 64; off <<= 1) s += __shfl_xor(s, off);
    const float inv = 1.f / (s + 1e-16f);

    const int grp = lane >> 4, sub = lane & 15;
    float acc[8] = {0.f, 0.f, 0.f, 0.f, 0.f, 0.f, 0.f, 0.f};
    for (int k = grp; k < deg; k += 4) {
        const int e = perm[base + k];
        const float wgt = __expf(gate[e] - m) * inv;
        const uint4 mv = *(const uint4*)(msgbuf + (size_t)e * DIM + sub * 8);
        acc[0] += wgt * bf_lo(mv.x); acc[1] += wgt * bf_hi(mv.x);
        acc[2] += wgt * bf_lo(mv.y); acc[3] += wgt * bf_hi(mv.y);
        acc[4] += wgt * bf_lo(mv.z); acc[5] += wgt * bf_hi(mv.z);
        acc[6] += wgt * bf_lo(mv.w); acc[7] += wgt * bf_hi(mv.w);
    }
    #pragma unroll
    for (int j = 0; j < 8; ++j) {
        acc[j] += __shfl_xor(acc[j], 16);
        acc[j] += __shfl_xor(acc[j], 32);
    }

    const float4 s0 = *(const float4*)(skip + (size_t)n * DIM + sub * 8);
    const float4 s1 = *(const float4*)(skip + (size_t)n * DIM + sub * 8 + 4);
    float v[8];
    v[0] = acc[0] + s0.x; v[1] = acc[1] + s0.y; v[2] = acc[2] + s0.z; v[3] = acc[3] + s0.w;
    v[4] = acc[4] + s1.x; v[5] = acc[5] + s1.y; v[6] = acc[6] + s1.z; v[7] = acc[7] + s1.w;

    float sum = 0.f, sq = 0.f;
    #pragma unroll
    for (int j = 0; j < 8; ++j) { sum += v[j]; sq += v[j] * v[j]; }
    #pragma unroll
    for (int off = 1; off < 16; off <<= 1) {
        sum += __shfl_xor(sum, off);
        sq  += __shfl_xor(sq, off);
    }
    const float mu = sum * (1.f / 128.f);
    const float var = sq * (1.f / 128.f) - mu * mu;
    const float rs = rsqrtf(var + 1e-5f);

    if (grp == 0) {
        const float4 g0 = *(const float4*)(gamma + sub * 8);
        const float4 g1 = *(const float4*)(gamma + sub * 8 + 4);
        const float4 be0 = *(const float4*)(beta + sub * 8);
        const float4 be1 = *(const float4*)(beta + sub * 8 + 4);
        float4 o0, o1;
        o0.x = (v[0] - mu) * rs * g0.x + be0.x;
        o0.y = (v[1] - mu) * rs * g0.y + be0.y;
        o0.z = (v[2] - mu) * rs * g0.z + be0.z;
        o0.w = (v[3] - mu) * rs * g0.w + be0.w;
        o1.x = (v[4] - mu) * rs * g1.x + be1.x;
        o1.y = (v[5] - mu) * rs * g1.y + be1.y;
        o1.z = (v[6] - mu) * rs * g1.z + be1.z;
        o1.w = (v[7] - mu) * rs * g1.w + be1.w;
        *(float4*)(out + (size_t)n * DIM + sub * 8) = o0;
        *(float4*)(out + (size_t)n * DIM + sub * 8 + 4) = o1;
    }
}

// ---------------------------------------------------------------------------
extern "C" void kernel_launch(void* const* d_in, const int* in_sizes, int n_in,
                              void* d_out, int out_size, void* d_ws, size_t ws_size,
                              hipStream_t stream)
{
    const float* x     = (const float*)d_in[0];
    const int*   eidx  = (const int*)d_in[1];
    const float* Wsrc  = (const float*)d_in[2];
    const float* bsrc  = (const float*)d_in[3];
    const float* Wtgt  = (const float*)d_in[4];
    const float* Wskip = (const float*)d_in[5];
    const float* a0    = (const float*)d_in[6];
    const float* W1    = (const float*)d_in[7];
    const float* b1    = (const float*)d_in[8];
    const float* a1    = (const float*)d_in[9];
    const float* W2    = (const float*)d_in[10];
    const float* b2    = (const float*)d_in[11];
    const float* Wg    = (const float*)d_in[12];
    const float* gamma = (const float*)d_in[13];
    const float* beta  = (const float*)d_in[14];

    const int N = in_sizes[0] / DIM;      // 20000
    const int E = in_sizes[1] / 2;        // 640000
    float* out = (float*)d_out;

    char* ws = (char*)d_ws;
    size_t off = 0;
    auto alloc = [&](size_t bytes) -> void* {
        void* p = ws + off;
        off += (bytes + 255) & ~(size_t)255;
        return p;
    };
    float*          msg_src = (float*)alloc((size_t)N * DIM * 4);
    float*          msg_tgt = (float*)alloc((size_t)N * DIM * 4);
    float*          skip    = (float*)alloc((size_t)N * DIM * 4);
    float*          gate    = (float*)alloc((size_t)E * 4);
    int*            deg     = (int*)alloc((size_t)N * 4);
    int*            rowptr  = (int*)alloc((size_t)(N + 1) * 4);
    int*            cursor  = (int*)alloc((size_t)N * 4);
    int*            perm    = (int*)alloc((size_t)E * 4);
    unsigned short* W1t     = (unsigned short*)alloc((size_t)DIM * DIM * 2);
    unsigned short* W2t     = (unsigned short*)alloc((size_t)DIM * DIM * 2);
    unsigned short* msgbuf  = (unsigned short*)alloc((size_t)E * DIM * 2);
    (void)ws_size; (void)n_in; (void)out_size;

    hipMemsetAsync(deg, 0, (size_t)N * 4, stream);

    prep_w_k<<<(2 * DIM * DIM + 255) / 256, 256, 0, stream>>>(W1, W2, W1t, W2t);

    hist_k<<<(E + 255) / 256, 256, 0, stream>>>(eidx, E, deg);
    scan_k<<<1, 256, 0, stream>>>(deg, rowptr, cursor, N);
    scatter_k<<<(E + 255) / 256, 256, 0, stream>>>(eidx, E, cursor, perm);

    node_linear<<<N / 32, 256, 0, stream>>>(x, Wsrc, bsrc, Wtgt, Wskip, msg_src, msg_tgt, skip);

    edge_mlp_mfma<<<E / 64, 256, 0, stream>>>(eidx, E, msg_src, msg_tgt, a0, W1t, b1, a1,
                                              W2t, b2, Wg, msgbuf, gate);

    aggregate_ln_k<<<(N + 3) / 4, 256, 0, stream>>>(rowptr, perm, gate, msgbuf, skip,
                                                    gamma, beta, out, N);
}

// Round 5
// 424.426 us; speedup vs baseline: 7.2602x; 1.0910x over previous
//
#include <hip/hip_runtime.h>
#include <hip/hip_bf16.h>
#include <stdint.h>

// Problem constants (reference: N=20000, E=640000, C=D=M=128)
#define DIM 128
#define HSTR 136   // padded LDS row stride in bf16 elems (272 B)

using bfrag = __attribute__((ext_vector_type(8))) short;   // 8 bf16 (4 VGPRs)
using f32x4 = __attribute__((ext_vector_type(4))) float;   // MFMA C/D

__device__ __forceinline__ float prelu_f(float v, float a) { return v >= 0.f ? v : a * v; }

__device__ __forceinline__ unsigned short f2bf(float f) {
    unsigned u = __float_as_uint(f);
    unsigned r = (u + 0x7FFFu + ((u >> 16) & 1u)) >> 16;   // RNE
    return (unsigned short)r;
}
__device__ __forceinline__ float bf_lo(unsigned u) { return __uint_as_float(u << 16); }
__device__ __forceinline__ float bf_hi(unsigned u) { return __uint_as_float(u & 0xFFFF0000u); }

// ---------------------------------------------------------------------------
// K1: msg_src = bf16(x@W_src + b_src) ; msg_tgt = bf16(x@W_tgt) ; skip = x@W_skip
// ---------------------------------------------------------------------------
__global__ __launch_bounds__(256) void node_linear(
    const float* __restrict__ x,
    const float* __restrict__ Wsrc, const float* __restrict__ bsrc,
    const float* __restrict__ Wtgt, const float* __restrict__ Wskip,
    unsigned short* __restrict__ msg_src, unsigned short* __restrict__ msg_tgt,
    float* __restrict__ skip)
{
    __shared__ float xs[32 * DIM];
    const int t = threadIdx.x;
    const int n0 = blockIdx.x * 32;

    const float4* xg = (const float4*)(x + (size_t)n0 * DIM);
    float4* xsv = (float4*)xs;
    for (int k = t; k < 32 * DIM / 4; k += 256) xsv[k] = xg[k];
    __syncthreads();

    const int dq = t & 31;
    const int nb = t >> 5;

    const float* Ws[3] = {Wsrc, Wtgt, Wskip};

    for (int mtx = 0; mtx < 3; ++mtx) {
        const float4* W4 = (const float4*)Ws[mtx];
        float acc[4][4];
        #pragma unroll
        for (int u = 0; u < 4; ++u)
            #pragma unroll
            for (int v = 0; v < 4; ++v) acc[u][v] = 0.f;

        for (int c = 0; c < DIM; c += 4) {
            float4 w0 = W4[(c + 0) * 32 + dq];
            float4 w1 = W4[(c + 1) * 32 + dq];
            float4 w2 = W4[(c + 2) * 32 + dq];
            float4 w3 = W4[(c + 3) * 32 + dq];
            #pragma unroll
            for (int u = 0; u < 4; ++u) {
                const float4 xv = *(const float4*)(xs + (nb * 4 + u) * DIM + c);
                acc[u][0] += xv.x * w0.x; acc[u][0] += xv.y * w1.x; acc[u][0] += xv.z * w2.x; acc[u][0] += xv.w * w3.x;
                acc[u][1] += xv.x * w0.y; acc[u][1] += xv.y * w1.y; acc[u][1] += xv.z * w2.y; acc[u][1] += xv.w * w3.y;
                acc[u][2] += xv.x * w0.z; acc[u][2] += xv.y * w1.z; acc[u][2] += xv.z * w2.z; acc[u][2] += xv.w * w3.z;
                acc[u][3] += xv.x * w0.w; acc[u][3] += xv.y * w1.w; acc[u][3] += xv.z * w2.w; acc[u][3] += xv.w * w3.w;
            }
        }

        #pragma unroll
        for (int u = 0; u < 4; ++u) {
            const int n = n0 + nb * 4 + u;
            if (mtx == 2) {
                float4 o;
                o.x = acc[u][0]; o.y = acc[u][1]; o.z = acc[u][2]; o.w = acc[u][3];
                *(float4*)(skip + (size_t)n * DIM + 4 * dq) = o;
            } else {
                float bx = 0.f, by = 0.f, bz = 0.f, bw = 0.f;
                if (mtx == 0) {
                    const float4 bb = ((const float4*)bsrc)[dq];
                    bx = bb.x; by = bb.y; bz = bb.z; bw = bb.w;
                }
                ushort4 o;
                o.x = f2bf(acc[u][0] + bx);
                o.y = f2bf(acc[u][1] + by);
                o.z = f2bf(acc[u][2] + bz);
                o.w = f2bf(acc[u][3] + bw);
                unsigned short* dst = (mtx == 0) ? msg_src : msg_tgt;
                *(ushort4*)(dst + (size_t)n * DIM + 4 * dq) = o;
            }
        }
    }
}

// ---------------------------------------------------------------------------
// Weight prep: Wt[n][k] = bf16(W[k][n])  for W1, W2
// ---------------------------------------------------------------------------
__global__ __launch_bounds__(256) void prep_w_k(
    const float* __restrict__ W1, const float* __restrict__ W2,
    unsigned short* __restrict__ W1t, unsigned short* __restrict__ W2t)
{
    const int idx = blockIdx.x * 256 + threadIdx.x;
    if (idx >= 2 * DIM * DIM) return;
    const float* W = (idx < DIM * DIM) ? W1 : W2;
    unsigned short* O = (idx < DIM * DIM) ? W1t : W2t;
    const int r = idx & (DIM * DIM - 1);
    const int n = r >> 7, k = r & 127;
    O[r] = f2bf(W[k * DIM + n]);
}

// ---------------------------------------------------------------------------
// CSR build: histogram -> single-block scan -> scatter -> pair gather
// ---------------------------------------------------------------------------
__global__ __launch_bounds__(256) void hist_k(const int* __restrict__ eidx, int E,
                                              int* __restrict__ deg)
{
    const int e = blockIdx.x * 256 + threadIdx.x;
    if (e < E) atomicAdd(deg + eidx[(size_t)E + e], 1);
}

__global__ __launch_bounds__(256) void scan_k(const int* __restrict__ deg,
                                              int* __restrict__ rowptr,
                                              int* __restrict__ cursor, int N)
{
    __shared__ int part[256];
    const int t = threadIdx.x;
    const int chunk = (N + 255) / 256;
    const int lo = t * chunk;
    const int hi = min(lo + chunk, N);

    int s = 0;
    for (int k = lo; k < hi; ++k) s += deg[k];
    part[t] = s;
    __syncthreads();

    for (int off = 1; off < 256; off <<= 1) {
        int u = (t >= off) ? part[t - off] : 0;
        __syncthreads();
        part[t] += u;
        __syncthreads();
    }

    int run = part[t] - s;
    for (int k = lo; k < hi; ++k) {
        rowptr[k] = run;
        cursor[k] = run;
        run += deg[k];
    }
    if (t == 255) rowptr[N] = part[255];
}

__global__ __launch_bounds__(256) void scatter_k(const int* __restrict__ eidx, int E,
                                                 int* __restrict__ cursor,
                                                 int* __restrict__ perm)
{
    const int e = blockIdx.x * 256 + threadIdx.x;
    if (e < E) {
        const int i = eidx[(size_t)E + e];
        const int p = atomicAdd(cursor + i, 1);
        perm[p] = e;
    }
}

// jp[p] = src node of perm[p]; ip[p] = tgt node of perm[p]
__global__ __launch_bounds__(256) void pairs_k(const int* __restrict__ perm,
                                               const int* __restrict__ eidx, int E,
                                               int* __restrict__ jp, int* __restrict__ ip)
{
    const int p = blockIdx.x * 256 + threadIdx.x;
    if (p < E) {
        const int e = perm[p];
        jp[p] = eidx[e];
        ip[p] = eidx[(size_t)E + e];
    }
}

// ---------------------------------------------------------------------------
// K2: per-edge MLP + gate via bf16 MFMA, edges in CSR(perm) order.
// 64 edges/block, 4 waves; wave w owns feature slice [w*32, w*32+32).
// Transposed MFMA: D = mfma(Wt-frag as A, h-frag as B) -> D[feature][edge],
// so epilogues write 4 consecutive features per lane (vector writes).
// msgbuf/gate are written in perm order (slot index p).
// ---------------------------------------------------------------------------
__global__ __launch_bounds__(256) void edge_mlp_mfma(
    const int* __restrict__ jp, const int* __restrict__ ip, int E,
    const unsigned short* __restrict__ msg_src, const unsigned short* __restrict__ msg_tgt,
    const float* __restrict__ a0p,
    const unsigned short* __restrict__ W1t, const float* __restrict__ b1,
    const float* __restrict__ a1p,
    const unsigned short* __restrict__ W2t, const float* __restrict__ b2,
    const float* __restrict__ Wg,
    unsigned short* __restrict__ msgbuf,   // bf16 [E,128], perm order
    float* __restrict__ gate)              // perm order
{
    __shared__ unsigned short h1[64 * HSTR];
    __shared__ unsigned short h2[64 * HSTR];
    __shared__ int ji[64], ii[64];
    __shared__ float gate_part[4][64];

    const int t = threadIdx.x;
    const int p0 = blockIdx.x * 64;
    const float a0 = *a0p, a1 = *a1p;
    const int w = t >> 6, lane = t & 63, col = lane & 15, quad = lane >> 4;

    // Register-resident fragments: Wt rows n = w*32 + nt*16 + col.
    bfrag bw1[2][4], bw2[2][4];
    float4 b1q[2], b2q[2], wgq[2];
    #pragma unroll
    for (int nt = 0; nt < 2; ++nt) {
        const int n = w * 32 + nt * 16 + col;
        #pragma unroll
        for (int ks = 0; ks < 4; ++ks) {
            const int k0 = ks * 32 + quad * 8;
            bw1[nt][ks] = *(const bfrag*)(W1t + n * DIM + k0);
            bw2[nt][ks] = *(const bfrag*)(W2t + n * DIM + k0);
        }
        const int nq = w * 32 + nt * 16 + quad * 4;   // feature quad for D rows
        b1q[nt] = *(const float4*)(b1 + nq);
        b2q[nt] = *(const float4*)(b2 + nq);
        wgq[nt] = *(const float4*)(Wg + nq);
    }

    if (t < 64) {
        ji[t] = jp[p0 + t];
        ii[t] = ip[p0 + t];
    }
    __syncthreads();

    // gather (bf16) + prelu(a0) -> h1
    for (int k = t; k < 64 * 16; k += 256) {
        const int e = k >> 4, o = k & 15;
        const uint4 sv = *(const uint4*)(msg_src + (size_t)ji[e] * DIM + o * 8);
        const uint4 gv = *(const uint4*)(msg_tgt + (size_t)ii[e] * DIM + o * 8);
        uint4 hv;
        {
            unsigned short l, h;
            l = f2bf(prelu_f(bf_lo(sv.x) + bf_lo(gv.x), a0));
            h = f2bf(prelu_f(bf_hi(sv.x) + bf_hi(gv.x), a0));
            hv.x = (unsigned)l | ((unsigned)h << 16);
            l = f2bf(prelu_f(bf_lo(sv.y) + bf_lo(gv.y), a0));
            h = f2bf(prelu_f(bf_hi(sv.y) + bf_hi(gv.y), a0));
            hv.y = (unsigned)l | ((unsigned)h << 16);
            l = f2bf(prelu_f(bf_lo(sv.z) + bf_lo(gv.z), a0));
            h = f2bf(prelu_f(bf_hi(sv.z) + bf_hi(gv.z), a0));
            hv.z = (unsigned)l | ((unsigned)h << 16);
            l = f2bf(prelu_f(bf_lo(sv.w) + bf_lo(gv.w), a0));
            h = f2bf(prelu_f(bf_hi(sv.w) + bf_hi(gv.w), a0));
            hv.w = (unsigned)l | ((unsigned)h << 16);
        }
        *(uint4*)(h1 + e * HSTR + o * 8) = hv;
    }
    __syncthreads();

    // GEMM1 (transposed): D[n][m] = sum_k W1[k][n] * h1[m][k]
    {
        f32x4 acc[4][2];
        #pragma unroll
        for (int mt = 0; mt < 4; ++mt)
            #pragma unroll
            for (int nt = 0; nt < 2; ++nt)
                acc[mt][nt] = f32x4{0.f, 0.f, 0.f, 0.f};

        #pragma unroll
        for (int mt = 0; mt < 4; ++mt) {
            bfrag af[4];
            #pragma unroll
            for (int ks = 0; ks < 4; ++ks)
                af[ks] = *(const bfrag*)(h1 + (mt * 16 + col) * HSTR + ks * 32 + quad * 8);
            #pragma unroll
            for (int nt = 0; nt < 2; ++nt)
                #pragma unroll
                for (int ks = 0; ks < 4; ++ks)
                    acc[mt][nt] = __builtin_amdgcn_mfma_f32_16x16x32_bf16(
                        bw1[nt][ks], af[ks], acc[mt][nt], 0, 0, 0);
        }

        // epilogue: lane holds 4 consecutive features n0..n0+3 for edge m
        #pragma unroll
        for (int mt = 0; mt < 4; ++mt)
            #pragma unroll
            for (int nt = 0; nt < 2; ++nt) {
                const int m = mt * 16 + col;
                const int n0 = w * 32 + nt * 16 + quad * 4;
                ushort4 o;
                o.x = f2bf(prelu_f(acc[mt][nt][0] + b1q[nt].x, a1));
                o.y = f2bf(prelu_f(acc[mt][nt][1] + b1q[nt].y, a1));
                o.z = f2bf(prelu_f(acc[mt][nt][2] + b1q[nt].z, a1));
                o.w = f2bf(prelu_f(acc[mt][nt][3] + b1q[nt].w, a1));
                *(ushort4*)(h2 + m * HSTR + n0) = o;
            }
    }
    __syncthreads();

    // GEMM2 (transposed): msg[m][n] = sum_k h2[m][k] * W2[k][n]; gate = msg@Wg
    {
        f32x4 acc[4][2];
        #pragma unroll
        for (int mt = 0; mt < 4; ++mt)
            #pragma unroll
            for (int nt = 0; nt < 2; ++nt)
                acc[mt][nt] = f32x4{0.f, 0.f, 0.f, 0.f};

        #pragma unroll
        for (int mt = 0; mt < 4; ++mt) {
            bfrag af[4];
            #pragma unroll
            for (int ks = 0; ks < 4; ++ks)
                af[ks] = *(const bfrag*)(h2 + (mt * 16 + col) * HSTR + ks * 32 + quad * 8);
            #pragma unroll
            for (int nt = 0; nt < 2; ++nt)
                #pragma unroll
                for (int ks = 0; ks < 4; ++ks)
                    acc[mt][nt] = __builtin_amdgcn_mfma_f32_16x16x32_bf16(
                        bw2[nt][ks], af[ks], acc[mt][nt], 0, 0, 0);
        }

        #pragma unroll
        for (int mt = 0; mt < 4; ++mt) {
            const int m = mt * 16 + col;
            float g = 0.f;
            #pragma unroll
            for (int nt = 0; nt < 2; ++nt) {
                const int n0 = w * 32 + nt * 16 + quad * 4;
                const float m0 = acc[mt][nt][0] + b2q[nt].x;
                const float m1 = acc[mt][nt][1] + b2q[nt].y;
                const float m2 = acc[mt][nt][2] + b2q[nt].z;
                const float m3 = acc[mt][nt][3] + b2q[nt].w;
                ushort4 o;
                o.x = f2bf(m0); o.y = f2bf(m1); o.z = f2bf(m2); o.w = f2bf(m3);
                *(ushort4*)(msgbuf + (size_t)(p0 + m) * DIM + n0) = o;
                g += m0 * wgq[nt].x + m1 * wgq[nt].y + m2 * wgq[nt].z + m3 * wgq[nt].w;
            }
            g += __shfl_xor(g, 16);
            g += __shfl_xor(g, 32);
            if (quad == 0) gate_part[w][m] = g;
        }
    }
    __syncthreads();

    if (t < 64)
        gate[p0 + t] = gate_part[0][t] + gate_part[1][t] + gate_part[2][t] + gate_part[3][t];
}

// ---------------------------------------------------------------------------
// K4: wave-per-node softmax + aggregate + skip + LayerNorm.
// gate/msgbuf are in perm order -> fully contiguous per-node ranges.
// ---------------------------------------------------------------------------
__global__ __launch_bounds__(256) void aggregate_ln_k(
    const int* __restrict__ rowptr,
    const float* __restrict__ gate, const unsigned short* __restrict__ msgbuf,
    const float* __restrict__ skip,
    const float* __restrict__ gamma, const float* __restrict__ beta,
    float* __restrict__ out, int N)
{
    const int n = blockIdx.x * 4 + (threadIdx.x >> 6);
    const int lane = threadIdx.x & 63;
    if (n >= N) return;

    const int base = rowptr[n];
    const int deg = rowptr[n + 1] - base;

    float m = -INFINITY;
    for (int k = lane; k < deg; k += 64) m = fmaxf(m, gate[base + k]);
    #pragma unroll
    for (int off = 1; off < 64; off <<= 1) m = fmaxf(m, __shfl_xor(m, off));

    float s = 0.f;
    for (int k = lane; k < deg; k += 64) s += __expf(gate[base + k] - m);
    #pragma unroll
    for (int off = 1; off < 64; off <<= 1) s += __shfl_xor(s, off);
    const float inv = 1.f / (s + 1e-16f);

    const int grp = lane >> 4, sub = lane & 15;
    float acc[8] = {0.f, 0.f, 0.f, 0.f, 0.f, 0.f, 0.f, 0.f};
    for (int k = grp; k < deg; k += 4) {
        const float wgt = __expf(gate[base + k] - m) * inv;
        const uint4 mv = *(const uint4*)(msgbuf + (size_t)(base + k) * DIM + sub * 8);
        acc[0] += wgt * bf_lo(mv.x); acc[1] += wgt * bf_hi(mv.x);
        acc[2] += wgt * bf_lo(mv.y); acc[3] += wgt * bf_hi(mv.y);
        acc[4] += wgt * bf_lo(mv.z); acc[5] += wgt * bf_hi(mv.z);
        acc[6] += wgt * bf_lo(mv.w); acc[7] += wgt * bf_hi(mv.w);
    }
    #pragma unroll
    for (int j = 0; j < 8; ++j) {
        acc[j] += __shfl_xor(acc[j], 16);
        acc[j] += __shfl_xor(acc[j], 32);
    }

    const float4 s0 = *(const float4*)(skip + (size_t)n * DIM + sub * 8);
    const float4 s1 = *(const float4*)(skip + (size_t)n * DIM + sub * 8 + 4);
    float v[8];
    v[0] = acc[0] + s0.x; v[1] = acc[1] + s0.y; v[2] = acc[2] + s0.z; v[3] = acc[3] + s0.w;
    v[4] = acc[4] + s1.x; v[5] = acc[5] + s1.y; v[6] = acc[6] + s1.z; v[7] = acc[7] + s1.w;

    float sum = 0.f, sq = 0.f;
    #pragma unroll
    for (int j = 0; j < 8; ++j) { sum += v[j]; sq += v[j] * v[j]; }
    #pragma unroll
    for (int off = 1; off < 16; off <<= 1) {
        sum += __shfl_xor(sum, off);
        sq  += __shfl_xor(sq, off);
    }
    const float mu = sum * (1.f / 128.f);
    const float var = sq * (1.f / 128.f) - mu * mu;
    const float rs = rsqrtf(var + 1e-5f);

    if (grp == 0) {
        const float4 g0 = *(const float4*)(gamma + sub * 8);
        const float4 g1 = *(const float4*)(gamma + sub * 8 + 4);
        const float4 be0 = *(const float4*)(beta + sub * 8);
        const float4 be1 = *(const float4*)(beta + sub * 8 + 4);
        float4 o0, o1;
        o0.x = (v[0] - mu) * rs * g0.x + be0.x;
        o0.y = (v[1] - mu) * rs * g0.y + be0.y;
        o0.z = (v[2] - mu) * rs * g0.z + be0.z;
        o0.w = (v[3] - mu) * rs * g0.w + be0.w;
        o1.x = (v[4] - mu) * rs * g1.x + be1.x;
        o1.y = (v[5] - mu) * rs * g1.y + be1.y;
        o1.z = (v[6] - mu) * rs * g1.z + be1.z;
        o1.w = (v[7] - mu) * rs * g1.w + be1.w;
        *(float4*)(out + (size_t)n * DIM + sub * 8) = o0;
        *(float4*)(out + (size_t)n * DIM + sub * 8 + 4) = o1;
    }
}

// ---------------------------------------------------------------------------
extern "C" void kernel_launch(void* const* d_in, const int* in_sizes, int n_in,
                              void* d_out, int out_size, void* d_ws, size_t ws_size,
                              hipStream_t stream)
{
    const float* x     = (const float*)d_in[0];
    const int*   eidx  = (const int*)d_in[1];
    const float* Wsrc  = (const float*)d_in[2];
    const float* bsrc  = (const float*)d_in[3];
    const float* Wtgt  = (const float*)d_in[4];
    const float* Wskip = (const float*)d_in[5];
    const float* a0    = (const float*)d_in[6];
    const float* W1    = (const float*)d_in[7];
    const float* b1    = (const float*)d_in[8];
    const float* a1    = (const float*)d_in[9];
    const float* W2    = (const float*)d_in[10];
    const float* b2    = (const float*)d_in[11];
    const float* Wg    = (const float*)d_in[12];
    const float* gamma = (const float*)d_in[13];
    const float* beta  = (const float*)d_in[14];

    const int N = in_sizes[0] / DIM;      // 20000
    const int E = in_sizes[1] / 2;        // 640000
    float* out = (float*)d_out;

    char* ws = (char*)d_ws;
    size_t off = 0;
    auto alloc = [&](size_t bytes) -> void* {
        void* p = ws + off;
        off += (bytes + 255) & ~(size_t)255;
        return p;
    };
    unsigned short* msg_src = (unsigned short*)alloc((size_t)N * DIM * 2);
    unsigned short* msg_tgt = (unsigned short*)alloc((size_t)N * DIM * 2);
    float*          skip    = (float*)alloc((size_t)N * DIM * 4);
    float*          gate    = (float*)alloc((size_t)E * 4);
    int*            deg     = (int*)alloc((size_t)N * 4);
    int*            rowptr  = (int*)alloc((size_t)(N + 1) * 4);
    int*            cursor  = (int*)alloc((size_t)N * 4);
    int*            perm    = (int*)alloc((size_t)E * 4);
    int*            jp      = (int*)alloc((size_t)E * 4);
    int*            ip      = (int*)alloc((size_t)E * 4);
    unsigned short* W1t     = (unsigned short*)alloc((size_t)DIM * DIM * 2);
    unsigned short* W2t     = (unsigned short*)alloc((size_t)DIM * DIM * 2);
    unsigned short* msgbuf  = (unsigned short*)alloc((size_t)E * DIM * 2);
    (void)ws_size; (void)n_in; (void)out_size;

    hipMemsetAsync(deg, 0, (size_t)N * 4, stream);

    prep_w_k<<<(2 * DIM * DIM + 255) / 256, 256, 0, stream>>>(W1, W2, W1t, W2t);

    hist_k<<<(E + 255) / 256, 256, 0, stream>>>(eidx, E, deg);
    scan_k<<<1, 256, 0, stream>>>(deg, rowptr, cursor, N);
    scatter_k<<<(E + 255) / 256, 256, 0, stream>>>(eidx, E, cursor, perm);
    pairs_k<<<(E + 255) / 256, 256, 0, stream>>>(perm, eidx, E, jp, ip);

    node_linear<<<N / 32, 256, 0, stream>>>(x, Wsrc, bsrc, Wtgt, Wskip, msg_src, msg_tgt, skip);

    edge_mlp_mfma<<<E / 64, 256, 0, stream>>>(jp, ip, E, msg_src, msg_tgt, a0, W1t, b1, a1,
                                              W2t, b2, Wg, msgbuf, gate);

    aggregate_ln_k<<<(N + 3) / 4, 256, 0, stream>>>(rowptr, gate, msgbuf, skip,
                                                    gamma, beta, out, N);
}

// Round 6
// 381.549 us; speedup vs baseline: 8.0760x; 1.1124x over previous
//
#include <hip/hip_runtime.h>
#include <hip/hip_bf16.h>
#include <stdint.h>

// Problem constants (reference: N=20000, E=640000, C=D=M=128)
#define DIM 128
#define HSTR 136   // padded LDS row stride in bf16 elems (272 B)

using bfrag = __attribute__((ext_vector_type(8))) short;   // 8 bf16 (4 VGPRs)
using f32x4 = __attribute__((ext_vector_type(4))) float;   // MFMA C/D

__device__ __forceinline__ float prelu_f(float v, float a) { return v >= 0.f ? v : a * v; }

__device__ __forceinline__ unsigned short f2bf(float f) {
    unsigned u = __float_as_uint(f);
    unsigned r = (u + 0x7FFFu + ((u >> 16) & 1u)) >> 16;   // RNE
    return (unsigned short)r;
}
__device__ __forceinline__ float bf_lo(unsigned u) { return __uint_as_float(u << 16); }
__device__ __forceinline__ float bf_hi(unsigned u) { return __uint_as_float(u & 0xFFFF0000u); }

// ---------------------------------------------------------------------------
// K1: msg_src = bf16(x@W_src + b_src) ; msg_tgt = bf16(x@W_tgt) ; skip = x@W_skip
// ---------------------------------------------------------------------------
__global__ __launch_bounds__(256) void node_linear(
    const float* __restrict__ x,
    const float* __restrict__ Wsrc, const float* __restrict__ bsrc,
    const float* __restrict__ Wtgt, const float* __restrict__ Wskip,
    unsigned short* __restrict__ msg_src, unsigned short* __restrict__ msg_tgt,
    float* __restrict__ skip)
{
    __shared__ float xs[32 * DIM];
    const int t = threadIdx.x;
    const int n0 = blockIdx.x * 32;

    const float4* xg = (const float4*)(x + (size_t)n0 * DIM);
    float4* xsv = (float4*)xs;
    for (int k = t; k < 32 * DIM / 4; k += 256) xsv[k] = xg[k];
    __syncthreads();

    const int dq = t & 31;
    const int nb = t >> 5;

    const float* Ws[3] = {Wsrc, Wtgt, Wskip};

    for (int mtx = 0; mtx < 3; ++mtx) {
        const float4* W4 = (const float4*)Ws[mtx];
        float acc[4][4];
        #pragma unroll
        for (int u = 0; u < 4; ++u)
            #pragma unroll
            for (int v = 0; v < 4; ++v) acc[u][v] = 0.f;

        for (int c = 0; c < DIM; c += 4) {
            float4 w0 = W4[(c + 0) * 32 + dq];
            float4 w1 = W4[(c + 1) * 32 + dq];
            float4 w2 = W4[(c + 2) * 32 + dq];
            float4 w3 = W4[(c + 3) * 32 + dq];
            #pragma unroll
            for (int u = 0; u < 4; ++u) {
                const float4 xv = *(const float4*)(xs + (nb * 4 + u) * DIM + c);
                acc[u][0] += xv.x * w0.x; acc[u][0] += xv.y * w1.x; acc[u][0] += xv.z * w2.x; acc[u][0] += xv.w * w3.x;
                acc[u][1] += xv.x * w0.y; acc[u][1] += xv.y * w1.y; acc[u][1] += xv.z * w2.y; acc[u][1] += xv.w * w3.y;
                acc[u][2] += xv.x * w0.z; acc[u][2] += xv.y * w1.z; acc[u][2] += xv.z * w2.z; acc[u][2] += xv.w * w3.z;
                acc[u][3] += xv.x * w0.w; acc[u][3] += xv.y * w1.w; acc[u][3] += xv.z * w2.w; acc[u][3] += xv.w * w3.w;
            }
        }

        #pragma unroll
        for (int u = 0; u < 4; ++u) {
            const int n = n0 + nb * 4 + u;
            if (mtx == 2) {
                float4 o;
                o.x = acc[u][0]; o.y = acc[u][1]; o.z = acc[u][2]; o.w = acc[u][3];
                *(float4*)(skip + (size_t)n * DIM + 4 * dq) = o;
            } else {
                float bx = 0.f, by = 0.f, bz = 0.f, bw = 0.f;
                if (mtx == 0) {
                    const float4 bb = ((const float4*)bsrc)[dq];
                    bx = bb.x; by = bb.y; bz = bb.z; bw = bb.w;
                }
                ushort4 o;
                o.x = f2bf(acc[u][0] + bx);
                o.y = f2bf(acc[u][1] + by);
                o.z = f2bf(acc[u][2] + bz);
                o.w = f2bf(acc[u][3] + bw);
                unsigned short* dst = (mtx == 0) ? msg_src : msg_tgt;
                *(ushort4*)(dst + (size_t)n * DIM + 4 * dq) = o;
            }
        }
    }
}

// ---------------------------------------------------------------------------
// Weight prep: Wt[n][k] = bf16(W[k][n]) for W1, W2
// ---------------------------------------------------------------------------
__global__ __launch_bounds__(256) void prep_w_k(
    const float* __restrict__ W1, const float* __restrict__ W2,
    unsigned short* __restrict__ W1t, unsigned short* __restrict__ W2t)
{
    const int idx = blockIdx.x * 256 + threadIdx.x;
    if (idx >= 2 * DIM * DIM) return;
    const float* W = (idx < DIM * DIM) ? W1 : W2;
    unsigned short* O = (idx < DIM * DIM) ? W1t : W2t;
    const int r = idx & (DIM * DIM - 1);
    const int n = r >> 7, k = r & 127;
    O[r] = f2bf(W[k * DIM + n]);
}

// w2g[k] = sum_d W2[k][d]*Wg[d] ; w2g[128] = c2 = sum_d b2[d]*Wg[d]
__global__ __launch_bounds__(256) void prep_gate_k(
    const float* __restrict__ W2, const float* __restrict__ b2,
    const float* __restrict__ Wg, float* __restrict__ w2g)
{
    const int k = threadIdx.x;
    if (k < DIM) {
        float s = 0.f;
        for (int d = 0; d < DIM; ++d) s += W2[k * DIM + d] * Wg[d];
        w2g[k] = s;
    } else if (k == DIM) {
        float s = 0.f;
        for (int d = 0; d < DIM; ++d) s += b2[d] * Wg[d];
        w2g[DIM] = s;
    }
}

// ---------------------------------------------------------------------------
// CSR build: histogram -> single-block scan -> scatter (writes jp/ip directly)
// ---------------------------------------------------------------------------
__global__ __launch_bounds__(256) void hist_k(const int* __restrict__ eidx, int E,
                                              int* __restrict__ deg)
{
    const int e = blockIdx.x * 256 + threadIdx.x;
    if (e < E) atomicAdd(deg + eidx[(size_t)E + e], 1);
}

__global__ __launch_bounds__(256) void scan_k(const int* __restrict__ deg,
                                              int* __restrict__ rowptr,
                                              int* __restrict__ cursor, int N)
{
    __shared__ int part[256];
    const int t = threadIdx.x;
    const int chunk = (N + 255) / 256;
    const int lo = t * chunk;
    const int hi = min(lo + chunk, N);

    int s = 0;
    for (int k = lo; k < hi; ++k) s += deg[k];
    part[t] = s;
    __syncthreads();

    for (int off = 1; off < 256; off <<= 1) {
        int u = (t >= off) ? part[t - off] : 0;
        __syncthreads();
        part[t] += u;
        __syncthreads();
    }

    int run = part[t] - s;
    for (int k = lo; k < hi; ++k) {
        rowptr[k] = run;
        cursor[k] = run;
        run += deg[k];
    }
    if (t == 255) rowptr[N] = part[255];
}

__global__ __launch_bounds__(256) void scatter_k(const int* __restrict__ eidx, int E,
                                                 int* __restrict__ cursor,
                                                 int* __restrict__ jp, int* __restrict__ ip)
{
    const int e = blockIdx.x * 256 + threadIdx.x;
    if (e < E) {
        const int j = eidx[e];
        const int i = eidx[(size_t)E + e];
        const int p = atomicAdd(cursor + i, 1);
        jp[p] = j;
        ip[p] = i;
    }
}

// ---------------------------------------------------------------------------
// K2: per-edge GEMM1 + gate via bf16 MFMA, edges in CSR order.
// h2 = prelu(prelu(msg_src[j]+msg_tgt[i], a0) @ W1 + b1, a1)  -> h2buf (bf16)
// gate = h2 . w2g + c2                                        -> gate[]
// 64 edges/block, 4 waves; wave w owns feature slice [w*32, w*32+32).
// Transposed MFMA: D[feature][edge].
// ---------------------------------------------------------------------------
__global__ __launch_bounds__(256) void edge_mlp_mfma(
    const int* __restrict__ jp, const int* __restrict__ ip, int E,
    const unsigned short* __restrict__ msg_src, const unsigned short* __restrict__ msg_tgt,
    const float* __restrict__ a0p,
    const unsigned short* __restrict__ W1t, const float* __restrict__ b1,
    const float* __restrict__ a1p,
    const float* __restrict__ w2g,         // [129]: W2@Wg, c2
    unsigned short* __restrict__ h2buf,    // bf16 [E,128], perm order
    float* __restrict__ gate)              // perm order
{
    __shared__ unsigned short h1[64 * HSTR];
    __shared__ int ji[64], ii[64];
    __shared__ float gate_part[4][64];

    const int t = threadIdx.x;
    const int p0 = blockIdx.x * 64;
    const float a0 = *a0p, a1 = *a1p;
    const int w = t >> 6, lane = t & 63, col = lane & 15, quad = lane >> 4;

    // Register-resident W1 fragments + per-lane bias/gate quads.
    bfrag bw1[2][4];
    float4 b1q[2], wgq[2];
    #pragma unroll
    for (int nt = 0; nt < 2; ++nt) {
        const int n = w * 32 + nt * 16 + col;
        #pragma unroll
        for (int ks = 0; ks < 4; ++ks)
            bw1[nt][ks] = *(const bfrag*)(W1t + n * DIM + ks * 32 + quad * 8);
        const int nq = w * 32 + nt * 16 + quad * 4;
        b1q[nt] = *(const float4*)(b1 + nq);
        wgq[nt] = *(const float4*)(w2g + nq);
    }
    const float c2 = w2g[DIM];

    if (t < 64) {
        ji[t] = jp[p0 + t];
        ii[t] = ip[p0 + t];
    }
    __syncthreads();

    // gather (bf16) + prelu(a0) -> h1
    for (int k = t; k < 64 * 16; k += 256) {
        const int e = k >> 4, o = k & 15;
        const uint4 sv = *(const uint4*)(msg_src + (size_t)ji[e] * DIM + o * 8);
        const uint4 gv = *(const uint4*)(msg_tgt + (size_t)ii[e] * DIM + o * 8);
        uint4 hv;
        unsigned short l, h;
        l = f2bf(prelu_f(bf_lo(sv.x) + bf_lo(gv.x), a0));
        h = f2bf(prelu_f(bf_hi(sv.x) + bf_hi(gv.x), a0));
        hv.x = (unsigned)l | ((unsigned)h << 16);
        l = f2bf(prelu_f(bf_lo(sv.y) + bf_lo(gv.y), a0));
        h = f2bf(prelu_f(bf_hi(sv.y) + bf_hi(gv.y), a0));
        hv.y = (unsigned)l | ((unsigned)h << 16);
        l = f2bf(prelu_f(bf_lo(sv.z) + bf_lo(gv.z), a0));
        h = f2bf(prelu_f(bf_hi(sv.z) + bf_hi(gv.z), a0));
        hv.z = (unsigned)l | ((unsigned)h << 16);
        l = f2bf(prelu_f(bf_lo(sv.w) + bf_lo(gv.w), a0));
        h = f2bf(prelu_f(bf_hi(sv.w) + bf_hi(gv.w), a0));
        hv.w = (unsigned)l | ((unsigned)h << 16);
        *(uint4*)(h1 + e * HSTR + o * 8) = hv;
    }
    __syncthreads();

    // GEMM1 (transposed): D[n][m] = sum_k W1[k][n] * h1[m][k]
    f32x4 acc[4][2];
    #pragma unroll
    for (int mt = 0; mt < 4; ++mt)
        #pragma unroll
        for (int nt = 0; nt < 2; ++nt)
            acc[mt][nt] = f32x4{0.f, 0.f, 0.f, 0.f};

    #pragma unroll
    for (int mt = 0; mt < 4; ++mt) {
        bfrag af[4];
        #pragma unroll
        for (int ks = 0; ks < 4; ++ks)
            af[ks] = *(const bfrag*)(h1 + (mt * 16 + col) * HSTR + ks * 32 + quad * 8);
        #pragma unroll
        for (int nt = 0; nt < 2; ++nt)
            #pragma unroll
            for (int ks = 0; ks < 4; ++ks)
                acc[mt][nt] = __builtin_amdgcn_mfma_f32_16x16x32_bf16(
                    bw1[nt][ks], af[ks], acc[mt][nt], 0, 0, 0);
    }

    // epilogue: prelu -> h2buf (bf16), gate partial dot with w2g
    #pragma unroll
    for (int mt = 0; mt < 4; ++mt) {
        const int m = mt * 16 + col;
        float g = 0.f;
        #pragma unroll
        for (int nt = 0; nt < 2; ++nt) {
            const int n0 = w * 32 + nt * 16 + quad * 4;
            const float p0v = prelu_f(acc[mt][nt][0] + b1q[nt].x, a1);
            const float p1v = prelu_f(acc[mt][nt][1] + b1q[nt].y, a1);
            const float p2v = prelu_f(acc[mt][nt][2] + b1q[nt].z, a1);
            const float p3v = prelu_f(acc[mt][nt][3] + b1q[nt].w, a1);
            ushort4 o;
            o.x = f2bf(p0v); o.y = f2bf(p1v); o.z = f2bf(p2v); o.w = f2bf(p3v);
            *(ushort4*)(h2buf + (size_t)(p0 + m) * DIM + n0) = o;
            g += p0v * wgq[nt].x + p1v * wgq[nt].y + p2v * wgq[nt].z + p3v * wgq[nt].w;
        }
        g += __shfl_xor(g, 16);
        g += __shfl_xor(g, 32);
        if (quad == 0) gate_part[w][m] = g;
    }
    __syncthreads();

    if (t < 64)
        gate[p0 + t] = gate_part[0][t] + gate_part[1][t] + gate_part[2][t] + gate_part[3][t] + c2;
}

// ---------------------------------------------------------------------------
// K3: wave-per-node softmax + weighted h2 aggregation -> aggh2 (bf16 [Npad,128])
// ---------------------------------------------------------------------------
__global__ __launch_bounds__(256) void aggregate_h2_k(
    const int* __restrict__ rowptr,
    const float* __restrict__ gate, const unsigned short* __restrict__ h2buf,
    unsigned short* __restrict__ aggh2, int N)
{
    const int n = blockIdx.x * 4 + (threadIdx.x >> 6);
    const int lane = threadIdx.x & 63;
    if (n >= N) return;

    const int base = rowptr[n];
    const int deg = rowptr[n + 1] - base;

    float m = -INFINITY;
    for (int k = lane; k < deg; k += 64) m = fmaxf(m, gate[base + k]);
    #pragma unroll
    for (int off = 1; off < 64; off <<= 1) m = fmaxf(m, __shfl_xor(m, off));

    float s = 0.f;
    for (int k = lane; k < deg; k += 64) s += __expf(gate[base + k] - m);
    #pragma unroll
    for (int off = 1; off < 64; off <<= 1) s += __shfl_xor(s, off);
    const float inv = 1.f / (s + 1e-16f);

    const int grp = lane >> 4, sub = lane & 15;
    float acc[8] = {0.f, 0.f, 0.f, 0.f, 0.f, 0.f, 0.f, 0.f};
    for (int k = grp; k < deg; k += 4) {
        const float wgt = __expf(gate[base + k] - m) * inv;
        const uint4 mv = *(const uint4*)(h2buf + (size_t)(base + k) * DIM + sub * 8);
        acc[0] += wgt * bf_lo(mv.x); acc[1] += wgt * bf_hi(mv.x);
        acc[2] += wgt * bf_lo(mv.y); acc[3] += wgt * bf_hi(mv.y);
        acc[4] += wgt * bf_lo(mv.z); acc[5] += wgt * bf_hi(mv.z);
        acc[6] += wgt * bf_lo(mv.w); acc[7] += wgt * bf_hi(mv.w);
    }
    #pragma unroll
    for (int j = 0; j < 8; ++j) {
        acc[j] += __shfl_xor(acc[j], 16);
        acc[j] += __shfl_xor(acc[j], 32);
    }

    if (grp == 0) {
        uint4 o;
        o.x = (unsigned)f2bf(acc[0]) | ((unsigned)f2bf(acc[1]) << 16);
        o.y = (unsigned)f2bf(acc[2]) | ((unsigned)f2bf(acc[3]) << 16);
        o.z = (unsigned)f2bf(acc[4]) | ((unsigned)f2bf(acc[5]) << 16);
        o.w = (unsigned)f2bf(acc[6]) | ((unsigned)f2bf(acc[7]) << 16);
        *(uint4*)(aggh2 + (size_t)n * DIM + sub * 8) = o;
    }
}

// ---------------------------------------------------------------------------
// K4: out = LN(aggh2 @ W2 + b2 + skip) * gamma + beta, via bf16 MFMA.
// 64 nodes/block, 4 waves; wave w owns feature slice [w*32, w*32+32).
// Transposed MFMA: D[feature][node]. Cross-wave LN reduce in LDS.
// ---------------------------------------------------------------------------
__global__ __launch_bounds__(256) void node_out_k(
    const unsigned short* __restrict__ aggh2,
    const unsigned short* __restrict__ W2t, const float* __restrict__ b2,
    const float* __restrict__ skip,
    const float* __restrict__ gamma, const float* __restrict__ beta,
    float* __restrict__ out, int N)
{
    __shared__ unsigned short hh[64 * HSTR];
    __shared__ float ls1[4][4][16], ls2[4][4][16];

    const int t = threadIdx.x;
    const int n0blk = blockIdx.x * 64;
    const int w = t >> 6, lane = t & 63, col = lane & 15, quad = lane >> 4;

    // W2 fragments (A operand)
    bfrag bw2[2][4];
    float4 b2q[2];
    #pragma unroll
    for (int nt = 0; nt < 2; ++nt) {
        const int n = w * 32 + nt * 16 + col;
        #pragma unroll
        for (int ks = 0; ks < 4; ++ks)
            bw2[nt][ks] = *(const bfrag*)(W2t + n * DIM + ks * 32 + quad * 8);
        b2q[nt] = *(const float4*)(b2 + w * 32 + nt * 16 + quad * 4);
    }

    // stage aggh2 tile (contiguous rows)
    for (int k = t; k < 64 * 16; k += 256) {
        const int e = k >> 4, o = k & 15;
        uint4 v = make_uint4(0, 0, 0, 0);
        if (n0blk + e < N) v = *(const uint4*)(aggh2 + (size_t)(n0blk + e) * DIM + o * 8);
        *(uint4*)(hh + e * HSTR + o * 8) = v;
    }
    __syncthreads();

    // GEMM: D[d][node] = sum_k W2[k][d] * aggh2[node][k]
    f32x4 acc[4][2];
    #pragma unroll
    for (int mt = 0; mt < 4; ++mt)
        #pragma unroll
        for (int nt = 0; nt < 2; ++nt)
            acc[mt][nt] = f32x4{0.f, 0.f, 0.f, 0.f};

    #pragma unroll
    for (int mt = 0; mt < 4; ++mt) {
        bfrag af[4];
        #pragma unroll
        for (int ks = 0; ks < 4; ++ks)
            af[ks] = *(const bfrag*)(hh + (mt * 16 + col) * HSTR + ks * 32 + quad * 8);
        #pragma unroll
        for (int nt = 0; nt < 2; ++nt)
            #pragma unroll
            for (int ks = 0; ks < 4; ++ks)
                acc[mt][nt] = __builtin_amdgcn_mfma_f32_16x16x32_bf16(
                    bw2[nt][ks], af[ks], acc[mt][nt], 0, 0, 0);
    }

    // v = acc + b2 + skip; partial LN stats per (mt, node=col)
    float v[4][2][4];
    #pragma unroll
    for (int mt = 0; mt < 4; ++mt) {
        const int node = n0blk + mt * 16 + col;
        float s1 = 0.f, s2 = 0.f;
        #pragma unroll
        for (int nt = 0; nt < 2; ++nt) {
            const int f0 = w * 32 + nt * 16 + quad * 4;
            float4 sk = make_float4(0.f, 0.f, 0.f, 0.f);
            if (node < N) sk = *(const float4*)(skip + (size_t)node * DIM + f0);
            v[mt][nt][0] = acc[mt][nt][0] + b2q[nt].x + sk.x;
            v[mt][nt][1] = acc[mt][nt][1] + b2q[nt].y + sk.y;
            v[mt][nt][2] = acc[mt][nt][2] + b2q[nt].z + sk.z;
            v[mt][nt][3] = acc[mt][nt][3] + b2q[nt].w + sk.w;
            #pragma unroll
            for (int r = 0; r < 4; ++r) {
                s1 += v[mt][nt][r];
                s2 += v[mt][nt][r] * v[mt][nt][r];
            }
        }
        s1 += __shfl_xor(s1, 16); s1 += __shfl_xor(s1, 32);
        s2 += __shfl_xor(s2, 16); s2 += __shfl_xor(s2, 32);
        if (quad == 0) { ls1[w][mt][col] = s1; ls2[w][mt][col] = s2; }
    }
    __syncthreads();

    #pragma unroll
    for (int mt = 0; mt < 4; ++mt) {
        const int node = n0blk + mt * 16 + col;
        if (node >= N) continue;
        const float sum = ls1[0][mt][col] + ls1[1][mt][col] + ls1[2][mt][col] + ls1[3][mt][col];
        const float sq  = ls2[0][mt][col] + ls2[1][mt][col] + ls2[2][mt][col] + ls2[3][mt][col];
        const float mu = sum * (1.f / 128.f);
        const float var = sq * (1.f / 128.f) - mu * mu;
        const float rs = rsqrtf(var + 1e-5f);
        #pragma unroll
        for (int nt = 0; nt < 2; ++nt) {
            const int f0 = w * 32 + nt * 16 + quad * 4;
            const float4 gm = *(const float4*)(gamma + f0);
            const float4 bt = *(const float4*)(beta + f0);
            float4 o;
            o.x = (v[mt][nt][0] - mu) * rs * gm.x + bt.x;
            o.y = (v[mt][nt][1] - mu) * rs * gm.y + bt.y;
            o.z = (v[mt][nt][2] - mu) * rs * gm.z + bt.z;
            o.w = (v[mt][nt][3] - mu) * rs * gm.w + bt.w;
            *(float4*)(out + (size_t)node * DIM + f0) = o;
        }
    }
}

// ---------------------------------------------------------------------------
extern "C" void kernel_launch(void* const* d_in, const int* in_sizes, int n_in,
                              void* d_out, int out_size, void* d_ws, size_t ws_size,
                              hipStream_t stream)
{
    const float* x     = (const float*)d_in[0];
    const int*   eidx  = (const int*)d_in[1];
    const float* Wsrc  = (const float*)d_in[2];
    const float* bsrc  = (const float*)d_in[3];
    const float* Wtgt  = (const float*)d_in[4];
    const float* Wskip = (const float*)d_in[5];
    const float* a0    = (const float*)d_in[6];
    const float* W1    = (const float*)d_in[7];
    const float* b1    = (const float*)d_in[8];
    const float* a1    = (const float*)d_in[9];
    const float* W2    = (const float*)d_in[10];
    const float* b2    = (const float*)d_in[11];
    const float* Wg    = (const float*)d_in[12];
    const float* gamma = (const float*)d_in[13];
    const float* beta  = (const float*)d_in[14];

    const int N = in_sizes[0] / DIM;      // 20000
    const int E = in_sizes[1] / 2;        // 640000
    const int Npad = ((N + 63) / 64) * 64;
    float* out = (float*)d_out;

    char* ws = (char*)d_ws;
    size_t off = 0;
    auto alloc = [&](size_t bytes) -> void* {
        void* p = ws + off;
        off += (bytes + 255) & ~(size_t)255;
        return p;
    };
    unsigned short* msg_src = (unsigned short*)alloc((size_t)N * DIM * 2);
    unsigned short* msg_tgt = (unsigned short*)alloc((size_t)N * DIM * 2);
    float*          skip    = (float*)alloc((size_t)N * DIM * 4);
    float*          gate    = (float*)alloc((size_t)E * 4);
    int*            deg     = (int*)alloc((size_t)N * 4);
    int*            rowptr  = (int*)alloc((size_t)(N + 1) * 4);
    int*            cursor  = (int*)alloc((size_t)N * 4);
    int*            jp      = (int*)alloc((size_t)E * 4);
    int*            ip      = (int*)alloc((size_t)E * 4);
    unsigned short* W1t     = (unsigned short*)alloc((size_t)DIM * DIM * 2);
    unsigned short* W2t     = (unsigned short*)alloc((size_t)DIM * DIM * 2);
    float*          w2g     = (float*)alloc((size_t)(DIM + 1) * 4);
    unsigned short* aggh2   = (unsigned short*)alloc((size_t)Npad * DIM * 2);
    unsigned short* h2buf   = (unsigned short*)alloc((size_t)E * DIM * 2);
    (void)ws_size; (void)n_in; (void)out_size;

    hipMemsetAsync(deg, 0, (size_t)N * 4, stream);
    if (Npad > N)
        hipMemsetAsync(aggh2 + (size_t)N * DIM, 0, (size_t)(Npad - N) * DIM * 2, stream);

    prep_w_k<<<(2 * DIM * DIM + 255) / 256, 256, 0, stream>>>(W1, W2, W1t, W2t);
    prep_gate_k<<<1, 256, 0, stream>>>(W2, b2, Wg, w2g);

    hist_k<<<(E + 255) / 256, 256, 0, stream>>>(eidx, E, deg);
    scan_k<<<1, 256, 0, stream>>>(deg, rowptr, cursor, N);
    scatter_k<<<(E + 255) / 256, 256, 0, stream>>>(eidx, E, cursor, jp, ip);

    node_linear<<<N / 32, 256, 0, stream>>>(x, Wsrc, bsrc, Wtgt, Wskip, msg_src, msg_tgt, skip);

    edge_mlp_mfma<<<E / 64, 256, 0, stream>>>(jp, ip, E, msg_src, msg_tgt, a0, W1t, b1, a1,
                                              w2g, h2buf, gate);

    aggregate_h2_k<<<(N + 3) / 4, 256, 0, stream>>>(rowptr, gate, h2buf, aggh2, N);

    node_out_k<<<Npad / 64, 256, 0, stream>>>(aggh2, W2t, b2, skip, gamma, beta, out, N);
}

// Round 7
// 357.149 us; speedup vs baseline: 8.6278x; 1.0683x over previous
//
#include <hip/hip_runtime.h>
#include <hip/hip_bf16.h>
#include <stdint.h>

// Problem constants (reference: N=20000, E=640000, C=D=M=128)
#define DIM 128
#define HSTR 136   // padded LDS row stride in bf16 elems (272 B)

using bfrag = __attribute__((ext_vector_type(8))) short;   // 8 bf16 (4 VGPRs)
using f32x4 = __attribute__((ext_vector_type(4))) float;   // MFMA C/D

__device__ __forceinline__ float prelu_f(float v, float a) { return v >= 0.f ? v : a * v; }

// RNE bf16 (used in cold prep paths)
__device__ __forceinline__ unsigned short f2bf(float f) {
    unsigned u = __float_as_uint(f);
    unsigned r = (u + 0x7FFFu + ((u >> 16) & 1u)) >> 16;
    return (unsigned short)r;
}
// Hot path: round-half-up to bf16 and pack two -> one u32 (a->lo16, b->hi16).
// 2x v_add + 1x v_perm; differs from RNE only on exact 0.5-ulp ties.
__device__ __forceinline__ unsigned pkbf(float a, float b) {
    const unsigned ua = __float_as_uint(a) + 0x8000u;
    const unsigned ub = __float_as_uint(b) + 0x8000u;
    return __builtin_amdgcn_perm(ub, ua, 0x07060302u);
}
__device__ __forceinline__ float bf_lo(unsigned u) { return __uint_as_float(u << 16); }
__device__ __forceinline__ float bf_hi(unsigned u) { return __uint_as_float(u & 0xFFFF0000u); }

// ---------------------------------------------------------------------------
// Prep: Wall[m][n][k] = bf16(W_m[k][n]) for m in {Wsrc,Wtgt,Wskip,W1,W2};
// last block computes w2g[k] = sum_d W2[k][d]*Wg[d], w2g[128] = b2.Wg
// ---------------------------------------------------------------------------
__global__ __launch_bounds__(256) void prep_all_k(
    const float* __restrict__ Wsrc, const float* __restrict__ Wtgt,
    const float* __restrict__ Wskip, const float* __restrict__ W1,
    const float* __restrict__ W2, const float* __restrict__ b2,
    const float* __restrict__ Wg,
    unsigned short* __restrict__ Wall, float* __restrict__ w2g)
{
    const int nblk = (5 * DIM * DIM) / 256;   // 320
    if (blockIdx.x == nblk) {
        const int k = threadIdx.x;
        if (k < DIM) {
            float s = 0.f;
            for (int d = 0; d < DIM; ++d) s += W2[k * DIM + d] * Wg[d];
            w2g[k] = s;
        } else if (k == DIM) {
            float s = 0.f;
            for (int d = 0; d < DIM; ++d) s += b2[d] * Wg[d];
            w2g[DIM] = s;
        }
        return;
    }
    const int idx = blockIdx.x * 256 + threadIdx.x;
    const int m = idx >> 14;
    const int r = idx & 16383;
    const int n = r >> 7, k = r & 127;
    const float* W = (m == 0) ? Wsrc : (m == 1) ? Wtgt : (m == 2) ? Wskip : (m == 3) ? W1 : W2;
    Wall[idx] = f2bf(W[k * DIM + n]);
}

// ---------------------------------------------------------------------------
// CSR build: histogram -> single-block scan -> scatter (writes jp/ip directly)
// ---------------------------------------------------------------------------
__global__ __launch_bounds__(256) void hist_k(const int* __restrict__ eidx, int E,
                                              int* __restrict__ deg)
{
    const int e = blockIdx.x * 256 + threadIdx.x;
    if (e < E) atomicAdd(deg + eidx[(size_t)E + e], 1);
}

__global__ __launch_bounds__(256) void scan_k(const int* __restrict__ deg,
                                              int* __restrict__ rowptr,
                                              int* __restrict__ cursor, int N)
{
    __shared__ int part[256];
    const int t = threadIdx.x;
    const int chunk = (N + 255) / 256;
    const int lo = t * chunk;
    const int hi = min(lo + chunk, N);

    int s = 0;
    for (int k = lo; k < hi; ++k) s += deg[k];
    part[t] = s;
    __syncthreads();

    for (int off = 1; off < 256; off <<= 1) {
        int u = (t >= off) ? part[t - off] : 0;
        __syncthreads();
        part[t] += u;
        __syncthreads();
    }

    int run = part[t] - s;
    for (int k = lo; k < hi; ++k) {
        rowptr[k] = run;
        cursor[k] = run;
        run += deg[k];
    }
    if (t == 255) rowptr[N] = part[255];
}

__global__ __launch_bounds__(256) void scatter_k(const int* __restrict__ eidx, int E,
                                                 int* __restrict__ cursor,
                                                 int* __restrict__ jp, int* __restrict__ ip)
{
    const int e = blockIdx.x * 256 + threadIdx.x;
    if (e < E) {
        const int j = eidx[e];
        const int i = eidx[(size_t)E + e];
        const int p = atomicAdd(cursor + i, 1);
        jp[p] = j;
        ip[p] = i;
    }
}

// ---------------------------------------------------------------------------
// K1: node linears via MFMA. 32 nodes/block, 4 waves; wave w owns feature
// slice [w*32, w*32+32). D[feature][node].
//   msg_src = bf16(x@W_src + b_src); msg_tgt = bf16(x@W_tgt); skip = x@W_skip
// ---------------------------------------------------------------------------
__global__ __launch_bounds__(256) void node_linear_mfma(
    const float* __restrict__ x,
    const unsigned short* __restrict__ Wall,   // [0]=src,[1]=tgt,[2]=skip
    const float* __restrict__ bsrc,
    unsigned short* __restrict__ msg_src, unsigned short* __restrict__ msg_tgt,
    float* __restrict__ skip, int N)
{
    __shared__ unsigned short xt[32 * HSTR];
    const int t = threadIdx.x;
    const int n0blk = blockIdx.x * 32;
    const int w = t >> 6, lane = t & 63, col = lane & 15, quad = lane >> 4;

    // stage bf16(x) tile
    for (int k = t; k < 32 * 16; k += 256) {
        const int row = k >> 4, o = k & 15;
        uint4 v = make_uint4(0, 0, 0, 0);
        if (n0blk + row < N) {
            const float4 a = *(const float4*)(x + (size_t)(n0blk + row) * DIM + o * 8);
            const float4 b = *(const float4*)(x + (size_t)(n0blk + row) * DIM + o * 8 + 4);
            v.x = pkbf(a.x, a.y); v.y = pkbf(a.z, a.w);
            v.z = pkbf(b.x, b.y); v.w = pkbf(b.z, b.w);
        }
        *(uint4*)(xt + row * HSTR + o * 8) = v;
    }
    __syncthreads();

    bfrag af[2][4];
    #pragma unroll
    for (int mt = 0; mt < 2; ++mt)
        #pragma unroll
        for (int ks = 0; ks < 4; ++ks)
            af[mt][ks] = *(const bfrag*)(xt + (mt * 16 + col) * HSTR + ks * 32 + quad * 8);

    for (int m = 0; m < 3; ++m) {
        const unsigned short* Wt = Wall + m * DIM * DIM;
        bfrag bw[2][4];
        #pragma unroll
        for (int nt = 0; nt < 2; ++nt)
            #pragma unroll
            for (int ks = 0; ks < 4; ++ks)
                bw[nt][ks] = *(const bfrag*)(Wt + (w * 32 + nt * 16 + col) * DIM + ks * 32 + quad * 8);

        f32x4 acc[2][2];
        #pragma unroll
        for (int mt = 0; mt < 2; ++mt)
            #pragma unroll
            for (int nt = 0; nt < 2; ++nt)
                acc[mt][nt] = f32x4{0.f, 0.f, 0.f, 0.f};

        #pragma unroll
        for (int mt = 0; mt < 2; ++mt)
            #pragma unroll
            for (int nt = 0; nt < 2; ++nt)
                #pragma unroll
                for (int ks = 0; ks < 4; ++ks)
                    acc[mt][nt] = __builtin_amdgcn_mfma_f32_16x16x32_bf16(
                        bw[nt][ks], af[mt][ks], acc[mt][nt], 0, 0, 0);

        #pragma unroll
        for (int mt = 0; mt < 2; ++mt) {
            const int node = n0blk + mt * 16 + col;
            if (node >= N) continue;
            #pragma unroll
            for (int nt = 0; nt < 2; ++nt) {
                const int f0 = w * 32 + nt * 16 + quad * 4;
                if (m == 2) {
                    float4 o;
                    o.x = acc[mt][nt][0]; o.y = acc[mt][nt][1];
                    o.z = acc[mt][nt][2]; o.w = acc[mt][nt][3];
                    *(float4*)(skip + (size_t)node * DIM + f0) = o;
                } else {
                    float b0 = 0.f, b1v = 0.f, b2v = 0.f, b3v = 0.f;
                    if (m == 0) {
                        const float4 bb = *(const float4*)(bsrc + f0);
                        b0 = bb.x; b1v = bb.y; b2v = bb.z; b3v = bb.w;
                    }
                    uint2 o;
                    o.x = pkbf(acc[mt][nt][0] + b0, acc[mt][nt][1] + b1v);
                    o.y = pkbf(acc[mt][nt][2] + b2v, acc[mt][nt][3] + b3v);
                    unsigned short* dst = (m == 0) ? msg_src : msg_tgt;
                    *(uint2*)(dst + (size_t)node * DIM + f0) = o;
                }
            }
        }
    }
}

// ---------------------------------------------------------------------------
// K2: per-edge GEMM1 + gate via bf16 MFMA, edges in CSR order.
// h2 = prelu(prelu(msg_src[j]+msg_tgt[i], a0) @ W1 + b1, a1)  -> h2buf (bf16)
// gate = h2 . w2g + c2                                        -> gate[]
// ---------------------------------------------------------------------------
__global__ __launch_bounds__(256) void edge_mlp_mfma(
    const int* __restrict__ jp, const int* __restrict__ ip, int E,
    const unsigned short* __restrict__ msg_src, const unsigned short* __restrict__ msg_tgt,
    const float* __restrict__ a0p,
    const unsigned short* __restrict__ W1t, const float* __restrict__ b1,
    const float* __restrict__ a1p,
    const float* __restrict__ w2g,
    unsigned short* __restrict__ h2buf,
    float* __restrict__ gate)
{
    __shared__ unsigned short h1[64 * HSTR];
    __shared__ int ji[64], ii[64];
    __shared__ float gate_part[4][64];

    const int t = threadIdx.x;
    const int p0 = blockIdx.x * 64;
    const float a0 = *a0p, a1 = *a1p;
    const int w = t >> 6, lane = t & 63, col = lane & 15, quad = lane >> 4;

    bfrag bw1[2][4];
    float4 b1q[2], wgq[2];
    #pragma unroll
    for (int nt = 0; nt < 2; ++nt) {
        const int n = w * 32 + nt * 16 + col;
        #pragma unroll
        for (int ks = 0; ks < 4; ++ks)
            bw1[nt][ks] = *(const bfrag*)(W1t + n * DIM + ks * 32 + quad * 8);
        const int nq = w * 32 + nt * 16 + quad * 4;
        b1q[nt] = *(const float4*)(b1 + nq);
        wgq[nt] = *(const float4*)(w2g + nq);
    }
    const float c2 = w2g[DIM];

    if (t < 64) {
        ji[t] = jp[p0 + t];
        ii[t] = ip[p0 + t];
    }
    __syncthreads();

    // gather (bf16) + prelu(a0) -> h1
    for (int k = t; k < 64 * 16; k += 256) {
        const int e = k >> 4, o = k & 15;
        const uint4 sv = *(const uint4*)(msg_src + (size_t)ji[e] * DIM + o * 8);
        const uint4 gv = *(const uint4*)(msg_tgt + (size_t)ii[e] * DIM + o * 8);
        uint4 hv;
        hv.x = pkbf(prelu_f(bf_lo(sv.x) + bf_lo(gv.x), a0),
                    prelu_f(bf_hi(sv.x) + bf_hi(gv.x), a0));
        hv.y = pkbf(prelu_f(bf_lo(sv.y) + bf_lo(gv.y), a0),
                    prelu_f(bf_hi(sv.y) + bf_hi(gv.y), a0));
        hv.z = pkbf(prelu_f(bf_lo(sv.z) + bf_lo(gv.z), a0),
                    prelu_f(bf_hi(sv.z) + bf_hi(gv.z), a0));
        hv.w = pkbf(prelu_f(bf_lo(sv.w) + bf_lo(gv.w), a0),
                    prelu_f(bf_hi(sv.w) + bf_hi(gv.w), a0));
        *(uint4*)(h1 + e * HSTR + o * 8) = hv;
    }
    __syncthreads();

    f32x4 acc[4][2];
    #pragma unroll
    for (int mt = 0; mt < 4; ++mt)
        #pragma unroll
        for (int nt = 0; nt < 2; ++nt)
            acc[mt][nt] = f32x4{0.f, 0.f, 0.f, 0.f};

    #pragma unroll
    for (int mt = 0; mt < 4; ++mt) {
        bfrag af[4];
        #pragma unroll
        for (int ks = 0; ks < 4; ++ks)
            af[ks] = *(const bfrag*)(h1 + (mt * 16 + col) * HSTR + ks * 32 + quad * 8);
        #pragma unroll
        for (int nt = 0; nt < 2; ++nt)
            #pragma unroll
            for (int ks = 0; ks < 4; ++ks)
                acc[mt][nt] = __builtin_amdgcn_mfma_f32_16x16x32_bf16(
                    bw1[nt][ks], af[ks], acc[mt][nt], 0, 0, 0);
    }

    // epilogue: prelu -> h2buf (bf16), gate partial dot with w2g
    #pragma unroll
    for (int mt = 0; mt < 4; ++mt) {
        const int m = mt * 16 + col;
        float g = 0.f;
        #pragma unroll
        for (int nt = 0; nt < 2; ++nt) {
            const int n0 = w * 32 + nt * 16 + quad * 4;
            const float p0v = prelu_f(acc[mt][nt][0] + b1q[nt].x, a1);
            const float p1v = prelu_f(acc[mt][nt][1] + b1q[nt].y, a1);
            const float p2v = prelu_f(acc[mt][nt][2] + b1q[nt].z, a1);
            const float p3v = prelu_f(acc[mt][nt][3] + b1q[nt].w, a1);
            uint2 o;
            o.x = pkbf(p0v, p1v);
            o.y = pkbf(p2v, p3v);
            *(uint2*)(h2buf + (size_t)(p0 + m) * DIM + n0) = o;
            g += p0v * wgq[nt].x + p1v * wgq[nt].y + p2v * wgq[nt].z + p3v * wgq[nt].w;
        }
        g += __shfl_xor(g, 16);
        g += __shfl_xor(g, 32);
        if (quad == 0) gate_part[w][m] = g;
    }
    __syncthreads();

    if (t < 64)
        gate[p0 + t] = gate_part[0][t] + gate_part[1][t] + gate_part[2][t] + gate_part[3][t] + c2;
}

// ---------------------------------------------------------------------------
// K3: wave-per-node softmax + weighted h2 aggregation -> aggh2 (bf16)
// ---------------------------------------------------------------------------
__global__ __launch_bounds__(256) void aggregate_h2_k(
    const int* __restrict__ rowptr,
    const float* __restrict__ gate, const unsigned short* __restrict__ h2buf,
    unsigned short* __restrict__ aggh2, int N)
{
    const int n = blockIdx.x * 4 + (threadIdx.x >> 6);
    const int lane = threadIdx.x & 63;
    if (n >= N) return;

    const int base = rowptr[n];
    const int deg = rowptr[n + 1] - base;

    float m = -INFINITY;
    for (int k = lane; k < deg; k += 64) m = fmaxf(m, gate[base + k]);
    #pragma unroll
    for (int off = 1; off < 64; off <<= 1) m = fmaxf(m, __shfl_xor(m, off));

    float s = 0.f;
    for (int k = lane; k < deg; k += 64) s += __expf(gate[base + k] - m);
    #pragma unroll
    for (int off = 1; off < 64; off <<= 1) s += __shfl_xor(s, off);
    const float inv = 1.f / (s + 1e-16f);

    const int grp = lane >> 4, sub = lane & 15;
    float acc[8] = {0.f, 0.f, 0.f, 0.f, 0.f, 0.f, 0.f, 0.f};
    for (int k = grp; k < deg; k += 4) {
        const float wgt = __expf(gate[base + k] - m) * inv;
        const uint4 mv = *(const uint4*)(h2buf + (size_t)(base + k) * DIM + sub * 8);
        acc[0] += wgt * bf_lo(mv.x); acc[1] += wgt * bf_hi(mv.x);
        acc[2] += wgt * bf_lo(mv.y); acc[3] += wgt * bf_hi(mv.y);
        acc[4] += wgt * bf_lo(mv.z); acc[5] += wgt * bf_hi(mv.z);
        acc[6] += wgt * bf_lo(mv.w); acc[7] += wgt * bf_hi(mv.w);
    }
    #pragma unroll
    for (int j = 0; j < 8; ++j) {
        acc[j] += __shfl_xor(acc[j], 16);
        acc[j] += __shfl_xor(acc[j], 32);
    }

    if (grp == 0) {
        uint4 o;
        o.x = pkbf(acc[0], acc[1]);
        o.y = pkbf(acc[2], acc[3]);
        o.z = pkbf(acc[4], acc[5]);
        o.w = pkbf(acc[6], acc[7]);
        *(uint4*)(aggh2 + (size_t)n * DIM + sub * 8) = o;
    }
}

// ---------------------------------------------------------------------------
// K4: out = LN(aggh2 @ W2 + b2 + skip) * gamma + beta, via bf16 MFMA.
// ---------------------------------------------------------------------------
__global__ __launch_bounds__(256) void node_out_k(
    const unsigned short* __restrict__ aggh2,
    const unsigned short* __restrict__ W2t, const float* __restrict__ b2,
    const float* __restrict__ skip,
    const float* __restrict__ gamma, const float* __restrict__ beta,
    float* __restrict__ out, int N)
{
    __shared__ unsigned short hh[64 * HSTR];
    __shared__ float ls1[4][4][16], ls2[4][4][16];

    const int t = threadIdx.x;
    const int n0blk = blockIdx.x * 64;
    const int w = t >> 6, lane = t & 63, col = lane & 15, quad = lane >> 4;

    bfrag bw2[2][4];
    float4 b2q[2];
    #pragma unroll
    for (int nt = 0; nt < 2; ++nt) {
        const int n = w * 32 + nt * 16 + col;
        #pragma unroll
        for (int ks = 0; ks < 4; ++ks)
            bw2[nt][ks] = *(const bfrag*)(W2t + n * DIM + ks * 32 + quad * 8);
        b2q[nt] = *(const float4*)(b2 + w * 32 + nt * 16 + quad * 4);
    }

    for (int k = t; k < 64 * 16; k += 256) {
        const int e = k >> 4, o = k & 15;
        uint4 v = make_uint4(0, 0, 0, 0);
        if (n0blk + e < N) v = *(const uint4*)(aggh2 + (size_t)(n0blk + e) * DIM + o * 8);
        *(uint4*)(hh + e * HSTR + o * 8) = v;
    }
    __syncthreads();

    f32x4 acc[4][2];
    #pragma unroll
    for (int mt = 0; mt < 4; ++mt)
        #pragma unroll
        for (int nt = 0; nt < 2; ++nt)
            acc[mt][nt] = f32x4{0.f, 0.f, 0.f, 0.f};

    #pragma unroll
    for (int mt = 0; mt < 4; ++mt) {
        bfrag af[4];
        #pragma unroll
        for (int ks = 0; ks < 4; ++ks)
            af[ks] = *(const bfrag*)(hh + (mt * 16 + col) * HSTR + ks * 32 + quad * 8);
        #pragma unroll
        for (int nt = 0; nt < 2; ++nt)
            #pragma unroll
            for (int ks = 0; ks < 4; ++ks)
                acc[mt][nt] = __builtin_amdgcn_mfma_f32_16x16x32_bf16(
                    bw2[nt][ks], af[ks], acc[mt][nt], 0, 0, 0);
    }

    float v[4][2][4];
    #pragma unroll
    for (int mt = 0; mt < 4; ++mt) {
        const int node = n0blk + mt * 16 + col;
        float s1 = 0.f, s2 = 0.f;
        #pragma unroll
        for (int nt = 0; nt < 2; ++nt) {
            const int f0 = w * 32 + nt * 16 + quad * 4;
            float4 sk = make_float4(0.f, 0.f, 0.f, 0.f);
            if (node < N) sk = *(const float4*)(skip + (size_t)node * DIM + f0);
            v[mt][nt][0] = acc[mt][nt][0] + b2q[nt].x + sk.x;
            v[mt][nt][1] = acc[mt][nt][1] + b2q[nt].y + sk.y;
            v[mt][nt][2] = acc[mt][nt][2] + b2q[nt].z + sk.z;
            v[mt][nt][3] = acc[mt][nt][3] + b2q[nt].w + sk.w;
            #pragma unroll
            for (int r = 0; r < 4; ++r) {
                s1 += v[mt][nt][r];
                s2 += v[mt][nt][r] * v[mt][nt][r];
            }
        }
        s1 += __shfl_xor(s1, 16); s1 += __shfl_xor(s1, 32);
        s2 += __shfl_xor(s2, 16); s2 += __shfl_xor(s2, 32);
        if (quad == 0) { ls1[w][mt][col] = s1; ls2[w][mt][col] = s2; }
    }
    __syncthreads();

    #pragma unroll
    for (int mt = 0; mt < 4; ++mt) {
        const int node = n0blk + mt * 16 + col;
        if (node >= N) continue;
        const float sum = ls1[0][mt][col] + ls1[1][mt][col] + ls1[2][mt][col] + ls1[3][mt][col];
        const float sq  = ls2[0][mt][col] + ls2[1][mt][col] + ls2[2][mt][col] + ls2[3][mt][col];
        const float mu = sum * (1.f / 128.f);
        const float var = sq * (1.f / 128.f) - mu * mu;
        const float rs = rsqrtf(var + 1e-5f);
        #pragma unroll
        for (int nt = 0; nt < 2; ++nt) {
            const int f0 = w * 32 + nt * 16 + quad * 4;
            const float4 gm = *(const float4*)(gamma + f0);
            const float4 bt = *(const float4*)(beta + f0);
            float4 o;
            o.x = (v[mt][nt][0] - mu) * rs * gm.x + bt.x;
            o.y = (v[mt][nt][1] - mu) * rs * gm.y + bt.y;
            o.z = (v[mt][nt][2] - mu) * rs * gm.z + bt.z;
            o.w = (v[mt][nt][3] - mu) * rs * gm.w + bt.w;
            *(float4*)(out + (size_t)node * DIM + f0) = o;
        }
    }
}

// ---------------------------------------------------------------------------
extern "C" void kernel_launch(void* const* d_in, const int* in_sizes, int n_in,
                              void* d_out, int out_size, void* d_ws, size_t ws_size,
                              hipStream_t stream)
{
    const float* x     = (const float*)d_in[0];
    const int*   eidx  = (const int*)d_in[1];
    const float* Wsrc  = (const float*)d_in[2];
    const float* bsrc  = (const float*)d_in[3];
    const float* Wtgt  = (const float*)d_in[4];
    const float* Wskip = (const float*)d_in[5];
    const float* a0    = (const float*)d_in[6];
    const float* W1    = (const float*)d_in[7];
    const float* b1    = (const float*)d_in[8];
    const float* a1    = (const float*)d_in[9];
    const float* W2    = (const float*)d_in[10];
    const float* b2    = (const float*)d_in[11];
    const float* Wg    = (const float*)d_in[12];
    const float* gamma = (const float*)d_in[13];
    const float* beta  = (const float*)d_in[14];

    const int N = in_sizes[0] / DIM;      // 20000
    const int E = in_sizes[1] / 2;        // 640000
    const int Npad = ((N + 63) / 64) * 64;
    float* out = (float*)d_out;

    char* ws = (char*)d_ws;
    size_t off = 0;
    auto alloc = [&](size_t bytes) -> void* {
        void* p = ws + off;
        off += (bytes + 255) & ~(size_t)255;
        return p;
    };
    unsigned short* msg_src = (unsigned short*)alloc((size_t)N * DIM * 2);
    unsigned short* msg_tgt = (unsigned short*)alloc((size_t)N * DIM * 2);
    float*          skip    = (float*)alloc((size_t)N * DIM * 4);
    float*          gate    = (float*)alloc((size_t)E * 4);
    int*            deg     = (int*)alloc((size_t)N * 4);
    int*            rowptr  = (int*)alloc((size_t)(N + 1) * 4);
    int*            cursor  = (int*)alloc((size_t)N * 4);
    int*            jp      = (int*)alloc((size_t)E * 4);
    int*            ip      = (int*)alloc((size_t)E * 4);
    unsigned short* Wall    = (unsigned short*)alloc((size_t)5 * DIM * DIM * 2);
    float*          w2g     = (float*)alloc((size_t)(DIM + 1) * 4);
    unsigned short* aggh2   = (unsigned short*)alloc((size_t)Npad * DIM * 2);
    unsigned short* h2buf   = (unsigned short*)alloc((size_t)E * DIM * 2);
    (void)ws_size; (void)n_in; (void)out_size;

    hipMemsetAsync(deg, 0, (size_t)N * 4, stream);

    prep_all_k<<<(5 * DIM * DIM) / 256 + 1, 256, 0, stream>>>(
        Wsrc, Wtgt, Wskip, W1, W2, b2, Wg, Wall, w2g);

    hist_k<<<(E + 255) / 256, 256, 0, stream>>>(eidx, E, deg);
    scan_k<<<1, 256, 0, stream>>>(deg, rowptr, cursor, N);
    scatter_k<<<(E + 255) / 256, 256, 0, stream>>>(eidx, E, cursor, jp, ip);

    node_linear_mfma<<<(N + 31) / 32, 256, 0, stream>>>(
        x, Wall, bsrc, msg_src, msg_tgt, skip, N);

    edge_mlp_mfma<<<E / 64, 256, 0, stream>>>(jp, ip, E, msg_src, msg_tgt, a0,
                                              Wall + 3 * DIM * DIM, b1, a1,
                                              w2g, h2buf, gate);

    aggregate_h2_k<<<(N + 3) / 4, 256, 0, stream>>>(rowptr, gate, h2buf, aggh2, N);

    node_out_k<<<Npad / 64, 256, 0, stream>>>(aggh2, Wall + 4 * DIM * DIM, b2, skip,
                                              gamma, beta, out, N);
}

// Round 8
// 331.134 us; speedup vs baseline: 9.3056x; 1.0786x over previous
//
#include <hip/hip_runtime.h>
#include <hip/hip_bf16.h>
#include <stdint.h>

// Problem constants (reference: N=20000, E=640000, C=D=M=128)
#define DIM 128
#define HSTR 136   // padded LDS row stride in bf16 elems (272 B, 16B-aligned rows)

using bfrag = __attribute__((ext_vector_type(8))) short;   // 8 bf16 (4 VGPRs)
using f32x4 = __attribute__((ext_vector_type(4))) float;   // MFMA C/D

__device__ __forceinline__ float prelu_f(float v, float a) { return v >= 0.f ? v : a * v; }

// RNE bf16 (cold prep paths)
__device__ __forceinline__ unsigned short f2bf(float f) {
    unsigned u = __float_as_uint(f);
    unsigned r = (u + 0x7FFFu + ((u >> 16) & 1u)) >> 16;
    return (unsigned short)r;
}
// Hot path: round-half-up bf16, pack two -> u32 (a->lo16, b->hi16).
__device__ __forceinline__ unsigned pkbf(float a, float b) {
    const unsigned ua = __float_as_uint(a) + 0x8000u;
    const unsigned ub = __float_as_uint(b) + 0x8000u;
    return __builtin_amdgcn_perm(ub, ua, 0x07060302u);
}
__device__ __forceinline__ float bf_lo(unsigned u) { return __uint_as_float(u << 16); }
__device__ __forceinline__ float bf_hi(unsigned u) { return __uint_as_float(u & 0xFFFF0000u); }

// ---------------------------------------------------------------------------
// Prep: Wall[m][n][k] = bf16(W_m[k][n]) for m in {Wsrc,Wtgt,Wskip,W1,W2};
// last block computes w2g[k] = sum_d W2[k][d]*Wg[d], w2g[128] = b2.Wg
// ---------------------------------------------------------------------------
__global__ __launch_bounds__(256) void prep_all_k(
    const float* __restrict__ Wsrc, const float* __restrict__ Wtgt,
    const float* __restrict__ Wskip, const float* __restrict__ W1,
    const float* __restrict__ W2, const float* __restrict__ b2,
    const float* __restrict__ Wg,
    unsigned short* __restrict__ Wall, float* __restrict__ w2g)
{
    const int nblk = (5 * DIM * DIM) / 256;   // 320
    if (blockIdx.x == nblk) {
        const int k = threadIdx.x;
        if (k < DIM) {
            float s = 0.f;
            for (int d = 0; d < DIM; ++d) s += W2[k * DIM + d] * Wg[d];
            w2g[k] = s;
        } else if (k == DIM) {
            float s = 0.f;
            for (int d = 0; d < DIM; ++d) s += b2[d] * Wg[d];
            w2g[DIM] = s;
        }
        return;
    }
    const int idx = blockIdx.x * 256 + threadIdx.x;
    const int m = idx >> 14;
    const int r = idx & 16383;
    const int n = r >> 7, k = r & 127;
    const float* W = (m == 0) ? Wsrc : (m == 1) ? Wtgt : (m == 2) ? Wskip : (m == 3) ? W1 : W2;
    Wall[idx] = f2bf(W[k * DIM + n]);
}

// ---------------------------------------------------------------------------
// CSR build: histogram -> single-block scan -> scatter (writes jp/ip directly)
// ---------------------------------------------------------------------------
__global__ __launch_bounds__(256) void hist_k(const int* __restrict__ eidx, int E,
                                              int* __restrict__ deg)
{
    const int e = blockIdx.x * 256 + threadIdx.x;
    if (e < E) atomicAdd(deg + eidx[(size_t)E + e], 1);
}

__global__ __launch_bounds__(256) void scan_k(const int* __restrict__ deg,
                                              int* __restrict__ rowptr,
                                              int* __restrict__ cursor, int N)
{
    __shared__ int part[256];
    const int t = threadIdx.x;
    const int chunk = (N + 255) / 256;
    const int lo = t * chunk;
    const int hi = min(lo + chunk, N);

    int s = 0;
    for (int k = lo; k < hi; ++k) s += deg[k];
    part[t] = s;
    __syncthreads();

    for (int off = 1; off < 256; off <<= 1) {
        int u = (t >= off) ? part[t - off] : 0;
        __syncthreads();
        part[t] += u;
        __syncthreads();
    }

    int run = part[t] - s;
    for (int k = lo; k < hi; ++k) {
        rowptr[k] = run;
        cursor[k] = run;
        run += deg[k];
    }
    if (t == 255) rowptr[N] = part[255];
}

__global__ __launch_bounds__(256) void scatter_k(const int* __restrict__ eidx, int E,
                                                 int* __restrict__ cursor,
                                                 int* __restrict__ jp, int* __restrict__ ip)
{
    const int e = blockIdx.x * 256 + threadIdx.x;
    if (e < E) {
        const int j = eidx[e];
        const int i = eidx[(size_t)E + e];
        const int p = atomicAdd(cursor + i, 1);
        jp[p] = j;
        ip[p] = i;
    }
}

// ---------------------------------------------------------------------------
// K1: node linears via MFMA. 32 nodes/block, 4 waves. D[feature][node].
// ---------------------------------------------------------------------------
__global__ __launch_bounds__(256) void node_linear_mfma(
    const float* __restrict__ x,
    const unsigned short* __restrict__ Wall,   // [0]=src,[1]=tgt,[2]=skip
    const float* __restrict__ bsrc,
    unsigned short* __restrict__ msg_src, unsigned short* __restrict__ msg_tgt,
    float* __restrict__ skip, int N)
{
    __shared__ unsigned short xt[32 * HSTR];
    const int t = threadIdx.x;
    const int n0blk = blockIdx.x * 32;
    const int w = t >> 6, lane = t & 63, col = lane & 15, quad = lane >> 4;

    for (int k = t; k < 32 * 16; k += 256) {
        const int row = k >> 4, o = k & 15;
        uint4 v = make_uint4(0, 0, 0, 0);
        if (n0blk + row < N) {
            const float4 a = *(const float4*)(x + (size_t)(n0blk + row) * DIM + o * 8);
            const float4 b = *(const float4*)(x + (size_t)(n0blk + row) * DIM + o * 8 + 4);
            v.x = pkbf(a.x, a.y); v.y = pkbf(a.z, a.w);
            v.z = pkbf(b.x, b.y); v.w = pkbf(b.z, b.w);
        }
        *(uint4*)(xt + row * HSTR + o * 8) = v;
    }
    __syncthreads();

    bfrag af[2][4];
    #pragma unroll
    for (int mt = 0; mt < 2; ++mt)
        #pragma unroll
        for (int ks = 0; ks < 4; ++ks)
            af[mt][ks] = *(const bfrag*)(xt + (mt * 16 + col) * HSTR + ks * 32 + quad * 8);

    for (int m = 0; m < 3; ++m) {
        const unsigned short* Wt = Wall + m * DIM * DIM;
        bfrag bw[2][4];
        #pragma unroll
        for (int nt = 0; nt < 2; ++nt)
            #pragma unroll
            for (int ks = 0; ks < 4; ++ks)
                bw[nt][ks] = *(const bfrag*)(Wt + (w * 32 + nt * 16 + col) * DIM + ks * 32 + quad * 8);

        f32x4 acc[2][2];
        #pragma unroll
        for (int mt = 0; mt < 2; ++mt)
            #pragma unroll
            for (int nt = 0; nt < 2; ++nt)
                acc[mt][nt] = f32x4{0.f, 0.f, 0.f, 0.f};

        #pragma unroll
        for (int mt = 0; mt < 2; ++mt)
            #pragma unroll
            for (int nt = 0; nt < 2; ++nt)
                #pragma unroll
                for (int ks = 0; ks < 4; ++ks)
                    acc[mt][nt] = __builtin_amdgcn_mfma_f32_16x16x32_bf16(
                        bw[nt][ks], af[mt][ks], acc[mt][nt], 0, 0, 0);

        #pragma unroll
        for (int mt = 0; mt < 2; ++mt) {
            const int node = n0blk + mt * 16 + col;
            if (node >= N) continue;
            #pragma unroll
            for (int nt = 0; nt < 2; ++nt) {
                const int f0 = w * 32 + nt * 16 + quad * 4;
                if (m == 2) {
                    float4 o;
                    o.x = acc[mt][nt][0]; o.y = acc[mt][nt][1];
                    o.z = acc[mt][nt][2]; o.w = acc[mt][nt][3];
                    *(float4*)(skip + (size_t)node * DIM + f0) = o;
                } else {
                    float b0 = 0.f, b1v = 0.f, b2v = 0.f, b3v = 0.f;
                    if (m == 0) {
                        const float4 bb = *(const float4*)(bsrc + f0);
                        b0 = bb.x; b1v = bb.y; b2v = bb.z; b3v = bb.w;
                    }
                    uint2 o;
                    o.x = pkbf(acc[mt][nt][0] + b0, acc[mt][nt][1] + b1v);
                    o.y = pkbf(acc[mt][nt][2] + b2v, acc[mt][nt][3] + b3v);
                    unsigned short* dst = (m == 0) ? msg_src : msg_tgt;
                    *(uint2*)(dst + (size_t)node * DIM + f0) = o;
                }
            }
        }
    }
}

// ---------------------------------------------------------------------------
// K2: persistent, software-pipelined per-edge GEMM1 + gate.
// Grid-stride over 64-edge tiles; double-buffered LDS h1; register prefetch
// of random msg_src rows one tile ahead; idx prefetch two tiles ahead;
// ONE barrier per tile (gate reduction deferred to next iteration).
// ---------------------------------------------------------------------------
__global__ __launch_bounds__(256, 3) void edge_mlp_mfma(
    const int* __restrict__ jp, const int* __restrict__ ip, int E, int ntiles,
    const unsigned short* __restrict__ msg_src, const unsigned short* __restrict__ msg_tgt,
    const float* __restrict__ a0p,
    const unsigned short* __restrict__ W1t, const float* __restrict__ b1,
    const float* __restrict__ a1p,
    const float* __restrict__ w2g,
    unsigned short* __restrict__ h2buf,
    float* __restrict__ gate)
{
    __shared__ unsigned short h1[2][64 * HSTR];
    __shared__ float gate_part[2][4][64];

    const int t = threadIdx.x;
    const float a0 = *a0p, a1 = *a1p;
    const int w = t >> 6, lane = t & 63, col = lane & 15, quad = lane >> 4;
    const int o = t & 15, r0 = t >> 4;   // gather mapping: rows r0+16i, col chunk o

    bfrag bw1[2][4];
    float4 b1q[2], wgq[2];
    #pragma unroll
    for (int nt = 0; nt < 2; ++nt) {
        const int n = w * 32 + nt * 16 + col;
        #pragma unroll
        for (int ks = 0; ks < 4; ++ks)
            bw1[nt][ks] = *(const bfrag*)(W1t + n * DIM + ks * 32 + quad * 8);
        const int nq = w * 32 + nt * 16 + quad * 4;
        b1q[nt] = *(const float4*)(b1 + nq);
        wgq[nt] = *(const float4*)(w2g + nq);
    }
    const float c2 = w2g[DIM];
    const int stride = gridDim.x;

    int tile = blockIdx.x;
    if (tile >= ntiles) return;

    int jA[4], iA[4], jB[4], iB[4];
    uint4 svA[4], svB[4];

    // prologue: idx+src for tile0; idx for tile1
    {
        const int p0 = tile * 64;
        #pragma unroll
        for (int i = 0; i < 4; ++i) {
            jA[i] = jp[p0 + r0 + 16 * i];
            iA[i] = ip[p0 + r0 + 16 * i];
        }
        #pragma unroll
        for (int i = 0; i < 4; ++i)
            svA[i] = *(const uint4*)(msg_src + (size_t)jA[i] * DIM + o * 8);
        const int tn = tile + stride;
        const int p1 = (tn < ntiles ? tn : tile) * 64;
        #pragma unroll
        for (int i = 0; i < 4; ++i) {
            jB[i] = jp[p1 + r0 + 16 * i];
            iB[i] = ip[p1 + r0 + 16 * i];
        }
    }

    int buf = 0;
    int prev_p0 = -1;

    for (; tile < ntiles; tile += stride) {
        const int p0 = tile * 64;

        // 1. issue NEXT tile's random src loads (fly during processing phase)
        #pragma unroll
        for (int i = 0; i < 4; ++i)
            svB[i] = *(const uint4*)(msg_src + (size_t)jB[i] * DIM + o * 8);

        // 2. processing: tgt loads (L2-hot) + combine + LDS write
        #pragma unroll
        for (int i = 0; i < 4; ++i) {
            const uint4 gv = *(const uint4*)(msg_tgt + (size_t)iA[i] * DIM + o * 8);
            uint4 hv;
            hv.x = pkbf(prelu_f(bf_lo(svA[i].x) + bf_lo(gv.x), a0),
                        prelu_f(bf_hi(svA[i].x) + bf_hi(gv.x), a0));
            hv.y = pkbf(prelu_f(bf_lo(svA[i].y) + bf_lo(gv.y), a0),
                        prelu_f(bf_hi(svA[i].y) + bf_hi(gv.y), a0));
            hv.z = pkbf(prelu_f(bf_lo(svA[i].z) + bf_lo(gv.z), a0),
                        prelu_f(bf_hi(svA[i].z) + bf_hi(gv.z), a0));
            hv.w = pkbf(prelu_f(bf_lo(svA[i].w) + bf_lo(gv.w), a0),
                        prelu_f(bf_hi(svA[i].w) + bf_hi(gv.w), a0));
            *(uint4*)(h1[buf] + (r0 + 16 * i) * HSTR + o * 8) = hv;
        }

        // 3. rotate idx; prefetch idx for tile+2*stride
        #pragma unroll
        for (int i = 0; i < 4; ++i) { jA[i] = jB[i]; iA[i] = iB[i]; }
        {
            const int tnn = tile + 2 * stride;
            const int p2 = (tnn < ntiles ? tnn : tile) * 64;
            #pragma unroll
            for (int i = 0; i < 4; ++i) {
                jB[i] = jp[p2 + r0 + 16 * i];
                iB[i] = ip[p2 + r0 + 16 * i];
            }
        }

        __syncthreads();   // h1[buf] visible; (drains prefetches too — structural)

        // 3b. deferred gate write for PREVIOUS tile (parts in gate_part[buf^1])
        if (prev_p0 >= 0 && t < 64)
            gate[prev_p0 + t] = gate_part[1 - buf][0][t] + gate_part[1 - buf][1][t]
                              + gate_part[1 - buf][2][t] + gate_part[1 - buf][3][t] + c2;

        // 4. GEMM1 (transposed): D[n][m] = sum_k W1[k][n] * h1[m][k]
        f32x4 acc[4][2];
        #pragma unroll
        for (int mt = 0; mt < 4; ++mt)
            #pragma unroll
            for (int nt = 0; nt < 2; ++nt)
                acc[mt][nt] = f32x4{0.f, 0.f, 0.f, 0.f};

        #pragma unroll
        for (int mt = 0; mt < 4; ++mt) {
            bfrag af[4];
            #pragma unroll
            for (int ks = 0; ks < 4; ++ks)
                af[ks] = *(const bfrag*)(h1[buf] + (mt * 16 + col) * HSTR + ks * 32 + quad * 8);
            #pragma unroll
            for (int nt = 0; nt < 2; ++nt)
                #pragma unroll
                for (int ks = 0; ks < 4; ++ks)
                    acc[mt][nt] = __builtin_amdgcn_mfma_f32_16x16x32_bf16(
                        bw1[nt][ks], af[ks], acc[mt][nt], 0, 0, 0);
        }

        // 5. epilogue: prelu -> h2buf (bf16), gate partials -> gate_part[buf]
        #pragma unroll
        for (int mt = 0; mt < 4; ++mt) {
            const int m = mt * 16 + col;
            float g = 0.f;
            #pragma unroll
            for (int nt = 0; nt < 2; ++nt) {
                const int n0 = w * 32 + nt * 16 + quad * 4;
                const float p0v = prelu_f(acc[mt][nt][0] + b1q[nt].x, a1);
                const float p1v = prelu_f(acc[mt][nt][1] + b1q[nt].y, a1);
                const float p2v = prelu_f(acc[mt][nt][2] + b1q[nt].z, a1);
                const float p3v = prelu_f(acc[mt][nt][3] + b1q[nt].w, a1);
                uint2 ov;
                ov.x = pkbf(p0v, p1v);
                ov.y = pkbf(p2v, p3v);
                *(uint2*)(h2buf + (size_t)(p0 + m) * DIM + n0) = ov;
                g += p0v * wgq[nt].x + p1v * wgq[nt].y + p2v * wgq[nt].z + p3v * wgq[nt].w;
            }
            g += __shfl_xor(g, 16);
            g += __shfl_xor(g, 32);
            if (quad == 0) gate_part[buf][w][m] = g;
        }

        // 6. rotate src buffer (already drained by the barrier)
        #pragma unroll
        for (int i = 0; i < 4; ++i) svA[i] = svB[i];
        prev_p0 = p0;
        buf ^= 1;
    }

    __syncthreads();
    if (t < 64)
        gate[prev_p0 + t] = gate_part[1 - buf][0][t] + gate_part[1 - buf][1][t]
                          + gate_part[1 - buf][2][t] + gate_part[1 - buf][3][t] + c2;
}

// ---------------------------------------------------------------------------
// K3: wave-per-node softmax + weighted h2 aggregation -> aggh2 (bf16)
// ---------------------------------------------------------------------------
__global__ __launch_bounds__(256) void aggregate_h2_k(
    const int* __restrict__ rowptr,
    const float* __restrict__ gate, const unsigned short* __restrict__ h2buf,
    unsigned short* __restrict__ aggh2, int N)
{
    const int n = blockIdx.x * 4 + (threadIdx.x >> 6);
    const int lane = threadIdx.x & 63;
    if (n >= N) return;

    const int base = rowptr[n];
    const int deg = rowptr[n + 1] - base;

    float m = -INFINITY;
    for (int k = lane; k < deg; k += 64) m = fmaxf(m, gate[base + k]);
    #pragma unroll
    for (int off = 1; off < 64; off <<= 1) m = fmaxf(m, __shfl_xor(m, off));

    float s = 0.f;
    for (int k = lane; k < deg; k += 64) s += __expf(gate[base + k] - m);
    #pragma unroll
    for (int off = 1; off < 64; off <<= 1) s += __shfl_xor(s, off);
    const float inv = 1.f / (s + 1e-16f);

    const int grp = lane >> 4, sub = lane & 15;
    float acc[8] = {0.f, 0.f, 0.f, 0.f, 0.f, 0.f, 0.f, 0.f};
    for (int k = grp; k < deg; k += 4) {
        const float wgt = __expf(gate[base + k] - m) * inv;
        const uint4 mv = *(const uint4*)(h2buf + (size_t)(base + k) * DIM + sub * 8);
        acc[0] += wgt * bf_lo(mv.x); acc[1] += wgt * bf_hi(mv.x);
        acc[2] += wgt * bf_lo(mv.y); acc[3] += wgt * bf_hi(mv.y);
        acc[4] += wgt * bf_lo(mv.z); acc[5] += wgt * bf_hi(mv.z);
        acc[6] += wgt * bf_lo(mv.w); acc[7] += wgt * bf_hi(mv.w);
    }
    #pragma unroll
    for (int j = 0; j < 8; ++j) {
        acc[j] += __shfl_xor(acc[j], 16);
        acc[j] += __shfl_xor(acc[j], 32);
    }

    if (grp == 0) {
        uint4 ov;
        ov.x = pkbf(acc[0], acc[1]);
        ov.y = pkbf(acc[2], acc[3]);
        ov.z = pkbf(acc[4], acc[5]);
        ov.w = pkbf(acc[6], acc[7]);
        *(uint4*)(aggh2 + (size_t)n * DIM + sub * 8) = ov;
    }
}

// ---------------------------------------------------------------------------
// K4: out = LN(aggh2 @ W2 + b2 + skip) * gamma + beta, via bf16 MFMA.
// ---------------------------------------------------------------------------
__global__ __launch_bounds__(256) void node_out_k(
    const unsigned short* __restrict__ aggh2,
    const unsigned short* __restrict__ W2t, const float* __restrict__ b2,
    const float* __restrict__ skip,
    const float* __restrict__ gamma, const float* __restrict__ beta,
    float* __restrict__ out, int N)
{
    __shared__ unsigned short hh[64 * HSTR];
    __shared__ float ls1[4][4][16], ls2[4][4][16];

    const int t = threadIdx.x;
    const int n0blk = blockIdx.x * 64;
    const int w = t >> 6, lane = t & 63, col = lane & 15, quad = lane >> 4;

    bfrag bw2[2][4];
    float4 b2q[2];
    #pragma unroll
    for (int nt = 0; nt < 2; ++nt) {
        const int n = w * 32 + nt * 16 + col;
        #pragma unroll
        for (int ks = 0; ks < 4; ++ks)
            bw2[nt][ks] = *(const bfrag*)(W2t + n * DIM + ks * 32 + quad * 8);
        b2q[nt] = *(const float4*)(b2 + w * 32 + nt * 16 + quad * 4);
    }

    for (int k = t; k < 64 * 16; k += 256) {
        const int e = k >> 4, o = k & 15;
        uint4 v = make_uint4(0, 0, 0, 0);
        if (n0blk + e < N) v = *(const uint4*)(aggh2 + (size_t)(n0blk + e) * DIM + o * 8);
        *(uint4*)(hh + e * HSTR + o * 8) = v;
    }
    __syncthreads();

    f32x4 acc[4][2];
    #pragma unroll
    for (int mt = 0; mt < 4; ++mt)
        #pragma unroll
        for (int nt = 0; nt < 2; ++nt)
            acc[mt][nt] = f32x4{0.f, 0.f, 0.f, 0.f};

    #pragma unroll
    for (int mt = 0; mt < 4; ++mt) {
        bfrag af[4];
        #pragma unroll
        for (int ks = 0; ks < 4; ++ks)
            af[ks] = *(const bfrag*)(hh + (mt * 16 + col) * HSTR + ks * 32 + quad * 8);
        #pragma unroll
        for (int nt = 0; nt < 2; ++nt)
            #pragma unroll
            for (int ks = 0; ks < 4; ++ks)
                acc[mt][nt] = __builtin_amdgcn_mfma_f32_16x16x32_bf16(
                    bw2[nt][ks], af[ks], acc[mt][nt], 0, 0, 0);
    }

    float v[4][2][4];
    #pragma unroll
    for (int mt = 0; mt < 4; ++mt) {
        const int node = n0blk + mt * 16 + col;
        float s1 = 0.f, s2 = 0.f;
        #pragma unroll
        for (int nt = 0; nt < 2; ++nt) {
            const int f0 = w * 32 + nt * 16 + quad * 4;
            float4 sk = make_float4(0.f, 0.f, 0.f, 0.f);
            if (node < N) sk = *(const float4*)(skip + (size_t)node * DIM + f0);
            v[mt][nt][0] = acc[mt][nt][0] + b2q[nt].x + sk.x;
            v[mt][nt][1] = acc[mt][nt][1] + b2q[nt].y + sk.y;
            v[mt][nt][2] = acc[mt][nt][2] + b2q[nt].z + sk.z;
            v[mt][nt][3] = acc[mt][nt][3] + b2q[nt].w + sk.w;
            #pragma unroll
            for (int r = 0; r < 4; ++r) {
                s1 += v[mt][nt][r];
                s2 += v[mt][nt][r] * v[mt][nt][r];
            }
        }
        s1 += __shfl_xor(s1, 16); s1 += __shfl_xor(s1, 32);
        s2 += __shfl_xor(s2, 16); s2 += __shfl_xor(s2, 32);
        if (quad == 0) { ls1[w][mt][col] = s1; ls2[w][mt][col] = s2; }
    }
    __syncthreads();

    #pragma unroll
    for (int mt = 0; mt < 4; ++mt) {
        const int node = n0blk + mt * 16 + col;
        if (node >= N) continue;
        const float sum = ls1[0][mt][col] + ls1[1][mt][col] + ls1[2][mt][col] + ls1[3][mt][col];
        const float sq  = ls2[0][mt][col] + ls2[1][mt][col] + ls2[2][mt][col] + ls2[3][mt][col];
        const float mu = sum * (1.f / 128.f);
        const float var = sq * (1.f / 128.f) - mu * mu;
        const float rs = rsqrtf(var + 1e-5f);
        #pragma unroll
        for (int nt = 0; nt < 2; ++nt) {
            const int f0 = w * 32 + nt * 16 + quad * 4;
            const float4 gm = *(const float4*)(gamma + f0);
            const float4 bt = *(const float4*)(beta + f0);
            float4 ov;
            ov.x = (v[mt][nt][0] - mu) * rs * gm.x + bt.x;
            ov.y = (v[mt][nt][1] - mu) * rs * gm.y + bt.y;
            ov.z = (v[mt][nt][2] - mu) * rs * gm.z + bt.z;
            ov.w = (v[mt][nt][3] - mu) * rs * gm.w + bt.w;
            *(float4*)(out + (size_t)node * DIM + f0) = ov;
        }
    }
}

// ---------------------------------------------------------------------------
extern "C" void kernel_launch(void* const* d_in, const int* in_sizes, int n_in,
                              void* d_out, int out_size, void* d_ws, size_t ws_size,
                              hipStream_t stream)
{
    const float* x     = (const float*)d_in[0];
    const int*   eidx  = (const int*)d_in[1];
    const float* Wsrc  = (const float*)d_in[2];
    const float* bsrc  = (const float*)d_in[3];
    const float* Wtgt  = (const float*)d_in[4];
    const float* Wskip = (const float*)d_in[5];
    const float* a0    = (const float*)d_in[6];
    const float* W1    = (const float*)d_in[7];
    const float* b1    = (const float*)d_in[8];
    const float* a1    = (const float*)d_in[9];
    const float* W2    = (const float*)d_in[10];
    const float* b2    = (const float*)d_in[11];
    const float* Wg    = (const float*)d_in[12];
    const float* gamma = (const float*)d_in[13];
    const float* beta  = (const float*)d_in[14];

    const int N = in_sizes[0] / DIM;      // 20000
    const int E = in_sizes[1] / 2;        // 640000
    const int Npad = ((N + 63) / 64) * 64;
    float* out = (float*)d_out;

    char* ws = (char*)d_ws;
    size_t off = 0;
    auto alloc = [&](size_t bytes) -> void* {
        void* p = ws + off;
        off += (bytes + 255) & ~(size_t)255;
        return p;
    };
    unsigned short* msg_src = (unsigned short*)alloc((size_t)N * DIM * 2);
    unsigned short* msg_tgt = (unsigned short*)alloc((size_t)N * DIM * 2);
    float*          skip    = (float*)alloc((size_t)N * DIM * 4);
    float*          gate    = (float*)alloc((size_t)E * 4);
    int*            deg     = (int*)alloc((size_t)N * 4);
    int*            rowptr  = (int*)alloc((size_t)(N + 1) * 4);
    int*            cursor  = (int*)alloc((size_t)N * 4);
    int*            jp      = (int*)alloc((size_t)E * 4);
    int*            ip      = (int*)alloc((size_t)E * 4);
    unsigned short* Wall    = (unsigned short*)alloc((size_t)5 * DIM * DIM * 2);
    float*          w2g     = (float*)alloc((size_t)(DIM + 1) * 4);
    unsigned short* aggh2   = (unsigned short*)alloc((size_t)Npad * DIM * 2);
    unsigned short* h2buf   = (unsigned short*)alloc((size_t)E * DIM * 2);
    (void)ws_size; (void)n_in; (void)out_size;

    hipMemsetAsync(deg, 0, (size_t)N * 4, stream);

    prep_all_k<<<(5 * DIM * DIM) / 256 + 1, 256, 0, stream>>>(
        Wsrc, Wtgt, Wskip, W1, W2, b2, Wg, Wall, w2g);

    hist_k<<<(E + 255) / 256, 256, 0, stream>>>(eidx, E, deg);
    scan_k<<<1, 256, 0, stream>>>(deg, rowptr, cursor, N);
    scatter_k<<<(E + 255) / 256, 256, 0, stream>>>(eidx, E, cursor, jp, ip);

    node_linear_mfma<<<(N + 31) / 32, 256, 0, stream>>>(
        x, Wall, bsrc, msg_src, msg_tgt, skip, N);

    const int ntiles = E / 64;
    const int egrid = ntiles < 2048 ? ntiles : 2048;
    edge_mlp_mfma<<<egrid, 256, 0, stream>>>(jp, ip, E, ntiles, msg_src, msg_tgt, a0,
                                             Wall + 3 * DIM * DIM, b1, a1,
                                             w2g, h2buf, gate);

    aggregate_h2_k<<<(N + 3) / 4, 256, 0, stream>>>(rowptr, gate, h2buf, aggh2, N);

    node_out_k<<<Npad / 64, 256, 0, stream>>>(aggh2, Wall + 4 * DIM * DIM, b2, skip,
                                              gamma, beta, out, N);
}

// Round 9
// 292.301 us; speedup vs baseline: 10.5419x; 1.1329x over previous
//
#include <hip/hip_runtime.h>
#include <hip/hip_bf16.h>
#include <stdint.h>

// Problem constants (reference: N=20000, E=640000, C=D=M=128)
#define DIM 128
#define HSTR 136    // padded LDS row stride in bf16 elems (272 B, 16B-aligned rows)
#define NMAX 20224  // LDS-staged scan capacity (80.9 KB)

using bfrag = __attribute__((ext_vector_type(8))) short;   // 8 bf16 (4 VGPRs)
using f32x4 = __attribute__((ext_vector_type(4))) float;   // MFMA C/D

__device__ __forceinline__ float prelu_f(float v, float a) { return v >= 0.f ? v : a * v; }

// RNE bf16 (cold prep paths)
__device__ __forceinline__ unsigned short f2bf(float f) {
    unsigned u = __float_as_uint(f);
    unsigned r = (u + 0x7FFFu + ((u >> 16) & 1u)) >> 16;
    return (unsigned short)r;
}
// Hot path: round-half-up bf16, pack two -> u32 (a->lo16, b->hi16).
__device__ __forceinline__ unsigned pkbf(float a, float b) {
    const unsigned ua = __float_as_uint(a) + 0x8000u;
    const unsigned ub = __float_as_uint(b) + 0x8000u;
    return __builtin_amdgcn_perm(ub, ua, 0x07060302u);
}
__device__ __forceinline__ float bf_lo(unsigned u) { return __uint_as_float(u << 16); }
__device__ __forceinline__ float bf_hi(unsigned u) { return __uint_as_float(u & 0xFFFF0000u); }

// ---------------------------------------------------------------------------
// Merged prep + hist. Blocks [0, nhist): histogram of target nodes.
// Blocks [nhist, nhist+320): Wall[m][n][k] = bf16(W_m[k][n]). Block nhist+320: w2g.
// ---------------------------------------------------------------------------
__global__ __launch_bounds__(256) void prep_hist_k(
    const float* __restrict__ Wsrc, const float* __restrict__ Wtgt,
    const float* __restrict__ Wskip, const float* __restrict__ W1,
    const float* __restrict__ W2, const float* __restrict__ b2,
    const float* __restrict__ Wg,
    unsigned short* __restrict__ Wall, float* __restrict__ w2g,
    const int* __restrict__ eidx, int E, int* __restrict__ deg)
{
    const int nhist = (E + 255) / 256;
    if ((int)blockIdx.x < nhist) {
        const int e = blockIdx.x * 256 + threadIdx.x;
        if (e < E) atomicAdd(deg + eidx[(size_t)E + e], 1);
        return;
    }
    const int b = blockIdx.x - nhist;
    if (b == (5 * DIM * DIM) / 256) {   // 320: w2g block
        const int k = threadIdx.x;
        if (k < DIM) {
            float s = 0.f;
            for (int d = 0; d < DIM; ++d) s += W2[k * DIM + d] * Wg[d];
            w2g[k] = s;
        } else if (k == DIM) {
            float s = 0.f;
            for (int d = 0; d < DIM; ++d) s += b2[d] * Wg[d];
            w2g[DIM] = s;
        }
        return;
    }
    const int idx = b * 256 + threadIdx.x;
    const int m = idx >> 14;
    const int r = idx & 16383;
    const int n = r >> 7, k = r & 127;
    const float* W = (m == 0) ? Wsrc : (m == 1) ? Wtgt : (m == 2) ? Wskip : (m == 3) ? W1 : W2;
    Wall[idx] = f2bf(W[k * DIM + n]);
}

// ---------------------------------------------------------------------------
// Single-block scan, LDS-staged (coalesced global traffic).
// ---------------------------------------------------------------------------
__global__ __launch_bounds__(256) void scan_k(const int* __restrict__ deg,
                                              int* __restrict__ rowptr,
                                              int* __restrict__ cursor, int N)
{
    __shared__ int part[256];
    const int t = threadIdx.x;

    if (N <= NMAX) {
        __shared__ int s[NMAX];
        for (int k = t; k < N; k += 256) s[k] = deg[k];
        __syncthreads();

        const int chunk = (N + 255) / 256;
        const int lo = min(t * chunk, N), hi = min(lo + chunk, N);
        int sum = 0;
        for (int k = lo; k < hi; ++k) sum += s[k];
        part[t] = sum;
        __syncthreads();
        for (int off = 1; off < 256; off <<= 1) {
            int u = (t >= off) ? part[t - off] : 0;
            __syncthreads();
            part[t] += u;
            __syncthreads();
        }
        int run = part[t] - sum;
        for (int k = lo; k < hi; ++k) { const int d = s[k]; s[k] = run; run += d; }
        __syncthreads();
        for (int k = t; k < N; k += 256) {
            const int v = s[k];
            rowptr[k] = v;
            cursor[k] = v;
        }
        if (t == 0) rowptr[N] = part[255];
    } else {
        // fallback (uncoalesced) for oversized N
        const int chunk = (N + 255) / 256;
        const int lo = min(t * chunk, N), hi = min(lo + chunk, N);
        int s = 0;
        for (int k = lo; k < hi; ++k) s += deg[k];
        part[t] = s;
        __syncthreads();
        for (int off = 1; off < 256; off <<= 1) {
            int u = (t >= off) ? part[t - off] : 0;
            __syncthreads();
            part[t] += u;
            __syncthreads();
        }
        int run = part[t] - s;
        for (int k = lo; k < hi; ++k) {
            rowptr[k] = run;
            cursor[k] = run;
            run += deg[k];
        }
        if (t == 255) rowptr[N] = part[255];
    }
}

// ---------------------------------------------------------------------------
// Merged scatter + node_linear (independent work, co-scheduled in one dispatch).
// Blocks [0, nscatter): CSR scatter -> jip[p] = {j, i} (one 8-B write).
// Blocks [nscatter, ...): node linears via MFMA, 32 nodes/block.
// ---------------------------------------------------------------------------
__global__ __launch_bounds__(256) void scatter_node_k(
    const int* __restrict__ eidx, int E, int* __restrict__ cursor,
    int2* __restrict__ jip, int nscatter,
    const float* __restrict__ x,
    const unsigned short* __restrict__ Wall,   // [0]=src,[1]=tgt,[2]=skip
    const float* __restrict__ bsrc,
    unsigned short* __restrict__ msg_src, unsigned short* __restrict__ msg_tgt,
    float* __restrict__ skip, int N)
{
    if ((int)blockIdx.x < nscatter) {
        const int e = blockIdx.x * 256 + threadIdx.x;
        if (e < E) {
            const int j = eidx[e];
            const int i = eidx[(size_t)E + e];
            const int p = atomicAdd(cursor + i, 1);
            jip[p] = make_int2(j, i);
        }
        return;
    }

    __shared__ unsigned short xt[32 * HSTR];
    const int t = threadIdx.x;
    const int n0blk = (blockIdx.x - nscatter) * 32;
    const int w = t >> 6, lane = t & 63, col = lane & 15, quad = lane >> 4;

    for (int k = t; k < 32 * 16; k += 256) {
        const int row = k >> 4, o = k & 15;
        uint4 v = make_uint4(0, 0, 0, 0);
        if (n0blk + row < N) {
            const float4 a = *(const float4*)(x + (size_t)(n0blk + row) * DIM + o * 8);
            const float4 b = *(const float4*)(x + (size_t)(n0blk + row) * DIM + o * 8 + 4);
            v.x = pkbf(a.x, a.y); v.y = pkbf(a.z, a.w);
            v.z = pkbf(b.x, b.y); v.w = pkbf(b.z, b.w);
        }
        *(uint4*)(xt + row * HSTR + o * 8) = v;
    }
    __syncthreads();

    bfrag af[2][4];
    #pragma unroll
    for (int mt = 0; mt < 2; ++mt)
        #pragma unroll
        for (int ks = 0; ks < 4; ++ks)
            af[mt][ks] = *(const bfrag*)(xt + (mt * 16 + col) * HSTR + ks * 32 + quad * 8);

    for (int m = 0; m < 3; ++m) {
        const unsigned short* Wt = Wall + m * DIM * DIM;
        bfrag bw[2][4];
        #pragma unroll
        for (int nt = 0; nt < 2; ++nt)
            #pragma unroll
            for (int ks = 0; ks < 4; ++ks)
                bw[nt][ks] = *(const bfrag*)(Wt + (w * 32 + nt * 16 + col) * DIM + ks * 32 + quad * 8);

        f32x4 acc[2][2];
        #pragma unroll
        for (int mt = 0; mt < 2; ++mt)
            #pragma unroll
            for (int nt = 0; nt < 2; ++nt)
                acc[mt][nt] = f32x4{0.f, 0.f, 0.f, 0.f};

        #pragma unroll
        for (int mt = 0; mt < 2; ++mt)
            #pragma unroll
            for (int nt = 0; nt < 2; ++nt)
                #pragma unroll
                for (int ks = 0; ks < 4; ++ks)
                    acc[mt][nt] = __builtin_amdgcn_mfma_f32_16x16x32_bf16(
                        bw[nt][ks], af[mt][ks], acc[mt][nt], 0, 0, 0);

        #pragma unroll
        for (int mt = 0; mt < 2; ++mt) {
            const int node = n0blk + mt * 16 + col;
            if (node >= N) continue;
            #pragma unroll
            for (int nt = 0; nt < 2; ++nt) {
                const int f0 = w * 32 + nt * 16 + quad * 4;
                if (m == 2) {
                    float4 o;
                    o.x = acc[mt][nt][0]; o.y = acc[mt][nt][1];
                    o.z = acc[mt][nt][2]; o.w = acc[mt][nt][3];
                    *(float4*)(skip + (size_t)node * DIM + f0) = o;
                } else {
                    float b0 = 0.f, b1v = 0.f, b2v = 0.f, b3v = 0.f;
                    if (m == 0) {
                        const float4 bb = *(const float4*)(bsrc + f0);
                        b0 = bb.x; b1v = bb.y; b2v = bb.z; b3v = bb.w;
                    }
                    uint2 o;
                    o.x = pkbf(acc[mt][nt][0] + b0, acc[mt][nt][1] + b1v);
                    o.y = pkbf(acc[mt][nt][2] + b2v, acc[mt][nt][3] + b3v);
                    unsigned short* dst = (m == 0) ? msg_src : msg_tgt;
                    *(uint2*)(dst + (size_t)node * DIM + f0) = o;
                }
            }
        }
    }
}

// ---------------------------------------------------------------------------
// K2: persistent, software-pipelined per-edge GEMM1 + gate.
// ---------------------------------------------------------------------------
__global__ __launch_bounds__(256, 3) void edge_mlp_mfma(
    const int2* __restrict__ jip, int ntiles,
    const unsigned short* __restrict__ msg_src, const unsigned short* __restrict__ msg_tgt,
    const float* __restrict__ a0p,
    const unsigned short* __restrict__ W1t, const float* __restrict__ b1,
    const float* __restrict__ a1p,
    const float* __restrict__ w2g,
    unsigned short* __restrict__ h2buf,
    float* __restrict__ gate)
{
    __shared__ unsigned short h1[2][64 * HSTR];
    __shared__ float gate_part[2][4][64];

    const int t = threadIdx.x;
    const float a0 = *a0p, a1 = *a1p;
    const int w = t >> 6, lane = t & 63, col = lane & 15, quad = lane >> 4;
    const int o = t & 15, r0 = t >> 4;

    bfrag bw1[2][4];
    float4 b1q[2], wgq[2];
    #pragma unroll
    for (int nt = 0; nt < 2; ++nt) {
        const int n = w * 32 + nt * 16 + col;
        #pragma unroll
        for (int ks = 0; ks < 4; ++ks)
            bw1[nt][ks] = *(const bfrag*)(W1t + n * DIM + ks * 32 + quad * 8);
        const int nq = w * 32 + nt * 16 + quad * 4;
        b1q[nt] = *(const float4*)(b1 + nq);
        wgq[nt] = *(const float4*)(w2g + nq);
    }
    const float c2 = w2g[DIM];
    const int stride = gridDim.x;

    int tile = blockIdx.x;
    if (tile >= ntiles) return;

    int2 eA[4], eB[4];
    uint4 svA[4], svB[4];

    {
        const int p0 = tile * 64;
        #pragma unroll
        for (int i = 0; i < 4; ++i) eA[i] = jip[p0 + r0 + 16 * i];
        #pragma unroll
        for (int i = 0; i < 4; ++i)
            svA[i] = *(const uint4*)(msg_src + (size_t)eA[i].x * DIM + o * 8);
        const int tn = tile + stride;
        const int p1 = (tn < ntiles ? tn : tile) * 64;
        #pragma unroll
        for (int i = 0; i < 4; ++i) eB[i] = jip[p1 + r0 + 16 * i];
    }

    int buf = 0;
    int prev_p0 = -1;

    for (; tile < ntiles; tile += stride) {
        const int p0 = tile * 64;

        // 1. issue NEXT tile's random src loads
        #pragma unroll
        for (int i = 0; i < 4; ++i)
            svB[i] = *(const uint4*)(msg_src + (size_t)eB[i].x * DIM + o * 8);

        // 2. processing: tgt loads (L2-hot) + combine + LDS write
        #pragma unroll
        for (int i = 0; i < 4; ++i) {
            const uint4 gv = *(const uint4*)(msg_tgt + (size_t)eA[i].y * DIM + o * 8);
            uint4 hv;
            hv.x = pkbf(prelu_f(bf_lo(svA[i].x) + bf_lo(gv.x), a0),
                        prelu_f(bf_hi(svA[i].x) + bf_hi(gv.x), a0));
            hv.y = pkbf(prelu_f(bf_lo(svA[i].y) + bf_lo(gv.y), a0),
                        prelu_f(bf_hi(svA[i].y) + bf_hi(gv.y), a0));
            hv.z = pkbf(prelu_f(bf_lo(svA[i].z) + bf_lo(gv.z), a0),
                        prelu_f(bf_hi(svA[i].z) + bf_hi(gv.z), a0));
            hv.w = pkbf(prelu_f(bf_lo(svA[i].w) + bf_lo(gv.w), a0),
                        prelu_f(bf_hi(svA[i].w) + bf_hi(gv.w), a0));
            *(uint4*)(h1[buf] + (r0 + 16 * i) * HSTR + o * 8) = hv;
        }

        // 3. rotate idx; prefetch idx for tile+2*stride
        #pragma unroll
        for (int i = 0; i < 4; ++i) eA[i] = eB[i];
        {
            const int tnn = tile + 2 * stride;
            const int p2 = (tnn < ntiles ? tnn : tile) * 64;
            #pragma unroll
            for (int i = 0; i < 4; ++i) eB[i] = jip[p2 + r0 + 16 * i];
        }

        __syncthreads();

        // 3b. deferred gate write for PREVIOUS tile
        if (prev_p0 >= 0 && t < 64)
            gate[prev_p0 + t] = gate_part[1 - buf][0][t] + gate_part[1 - buf][1][t]
                              + gate_part[1 - buf][2][t] + gate_part[1 - buf][3][t] + c2;

        // 4. GEMM1 (transposed)
        f32x4 acc[4][2];
        #pragma unroll
        for (int mt = 0; mt < 4; ++mt)
            #pragma unroll
            for (int nt = 0; nt < 2; ++nt)
                acc[mt][nt] = f32x4{0.f, 0.f, 0.f, 0.f};

        #pragma unroll
        for (int mt = 0; mt < 4; ++mt) {
            bfrag af[4];
            #pragma unroll
            for (int ks = 0; ks < 4; ++ks)
                af[ks] = *(const bfrag*)(h1[buf] + (mt * 16 + col) * HSTR + ks * 32 + quad * 8);
            #pragma unroll
            for (int nt = 0; nt < 2; ++nt)
                #pragma unroll
                for (int ks = 0; ks < 4; ++ks)
                    acc[mt][nt] = __builtin_amdgcn_mfma_f32_16x16x32_bf16(
                        bw1[nt][ks], af[ks], acc[mt][nt], 0, 0, 0);
        }

        // 5. epilogue: prelu -> h2buf, gate partials
        #pragma unroll
        for (int mt = 0; mt < 4; ++mt) {
            const int m = mt * 16 + col;
            float g = 0.f;
            #pragma unroll
            for (int nt = 0; nt < 2; ++nt) {
                const int n0 = w * 32 + nt * 16 + quad * 4;
                const float p0v = prelu_f(acc[mt][nt][0] + b1q[nt].x, a1);
                const float p1v = prelu_f(acc[mt][nt][1] + b1q[nt].y, a1);
                const float p2v = prelu_f(acc[mt][nt][2] + b1q[nt].z, a1);
                const float p3v = prelu_f(acc[mt][nt][3] + b1q[nt].w, a1);
                uint2 ov;
                ov.x = pkbf(p0v, p1v);
                ov.y = pkbf(p2v, p3v);
                *(uint2*)(h2buf + (size_t)(p0 + m) * DIM + n0) = ov;
                g += p0v * wgq[nt].x + p1v * wgq[nt].y + p2v * wgq[nt].z + p3v * wgq[nt].w;
            }
            g += __shfl_xor(g, 16);
            g += __shfl_xor(g, 32);
            if (quad == 0) gate_part[buf][w][m] = g;
        }

        #pragma unroll
        for (int i = 0; i < 4; ++i) svA[i] = svB[i];
        prev_p0 = p0;
        buf ^= 1;
    }

    __syncthreads();
    if (t < 64)
        gate[prev_p0 + t] = gate_part[1 - buf][0][t] + gate_part[1 - buf][1][t]
                          + gate_part[1 - buf][2][t] + gate_part[1 - buf][3][t] + c2;
}

// ---------------------------------------------------------------------------
// K3: wave-per-node softmax + weighted h2 aggregation -> aggh2 (bf16)
// ---------------------------------------------------------------------------
__global__ __launch_bounds__(256) void aggregate_h2_k(
    const int* __restrict__ rowptr,
    const float* __restrict__ gate, const unsigned short* __restrict__ h2buf,
    unsigned short* __restrict__ aggh2, int N)
{
    const int n = blockIdx.x * 4 + (threadIdx.x >> 6);
    const int lane = threadIdx.x & 63;
    if (n >= N) return;

    const int base = rowptr[n];
    const int deg = rowptr[n + 1] - base;

    float m = -INFINITY;
    for (int k = lane; k < deg; k += 64) m = fmaxf(m, gate[base + k]);
    #pragma unroll
    for (int off = 1; off < 64; off <<= 1) m = fmaxf(m, __shfl_xor(m, off));

    float s = 0.f;
    for (int k = lane; k < deg; k += 64) s += __expf(gate[base + k] - m);
    #pragma unroll
    for (int off = 1; off < 64; off <<= 1) s += __shfl_xor(s, off);
    const float inv = 1.f / (s + 1e-16f);

    const int grp = lane >> 4, sub = lane & 15;
    float acc[8] = {0.f, 0.f, 0.f, 0.f, 0.f, 0.f, 0.f, 0.f};
    for (int k = grp; k < deg; k += 4) {
        const float wgt = __expf(gate[base + k] - m) * inv;
        const uint4 mv = *(const uint4*)(h2buf + (size_t)(base + k) * DIM + sub * 8);
        acc[0] += wgt * bf_lo(mv.x); acc[1] += wgt * bf_hi(mv.x);
        acc[2] += wgt * bf_lo(mv.y); acc[3] += wgt * bf_hi(mv.y);
        acc[4] += wgt * bf_lo(mv.z); acc[5] += wgt * bf_hi(mv.z);
        acc[6] += wgt * bf_lo(mv.w); acc[7] += wgt * bf_hi(mv.w);
    }
    #pragma unroll
    for (int j = 0; j < 8; ++j) {
        acc[j] += __shfl_xor(acc[j], 16);
        acc[j] += __shfl_xor(acc[j], 32);
    }

    if (grp == 0) {
        uint4 ov;
        ov.x = pkbf(acc[0], acc[1]);
        ov.y = pkbf(acc[2], acc[3]);
        ov.z = pkbf(acc[4], acc[5]);
        ov.w = pkbf(acc[6], acc[7]);
        *(uint4*)(aggh2 + (size_t)n * DIM + sub * 8) = ov;
    }
}

// ---------------------------------------------------------------------------
// K4: out = LN(aggh2 @ W2 + b2 + skip) * gamma + beta, via bf16 MFMA.
// ---------------------------------------------------------------------------
__global__ __launch_bounds__(256) void node_out_k(
    const unsigned short* __restrict__ aggh2,
    const unsigned short* __restrict__ W2t, const float* __restrict__ b2,
    const float* __restrict__ skip,
    const float* __restrict__ gamma, const float* __restrict__ beta,
    float* __restrict__ out, int N)
{
    __shared__ unsigned short hh[64 * HSTR];
    __shared__ float ls1[4][4][16], ls2[4][4][16];

    const int t = threadIdx.x;
    const int n0blk = blockIdx.x * 64;
    const int w = t >> 6, lane = t & 63, col = lane & 15, quad = lane >> 4;

    bfrag bw2[2][4];
    float4 b2q[2];
    #pragma unroll
    for (int nt = 0; nt < 2; ++nt) {
        const int n = w * 32 + nt * 16 + col;
        #pragma unroll
        for (int ks = 0; ks < 4; ++ks)
            bw2[nt][ks] = *(const bfrag*)(W2t + n * DIM + ks * 32 + quad * 8);
        b2q[nt] = *(const float4*)(b2 + w * 32 + nt * 16 + quad * 4);
    }

    for (int k = t; k < 64 * 16; k += 256) {
        const int e = k >> 4, o = k & 15;
        uint4 v = make_uint4(0, 0, 0, 0);
        if (n0blk + e < N) v = *(const uint4*)(aggh2 + (size_t)(n0blk + e) * DIM + o * 8);
        *(uint4*)(hh + e * HSTR + o * 8) = v;
    }
    __syncthreads();

    f32x4 acc[4][2];
    #pragma unroll
    for (int mt = 0; mt < 4; ++mt)
        #pragma unroll
        for (int nt = 0; nt < 2; ++nt)
            acc[mt][nt] = f32x4{0.f, 0.f, 0.f, 0.f};

    #pragma unroll
    for (int mt = 0; mt < 4; ++mt) {
        bfrag af[4];
        #pragma unroll
        for (int ks = 0; ks < 4; ++ks)
            af[ks] = *(const bfrag*)(hh + (mt * 16 + col) * HSTR + ks * 32 + quad * 8);
        #pragma unroll
        for (int nt = 0; nt < 2; ++nt)
            #pragma unroll
            for (int ks = 0; ks < 4; ++ks)
                acc[mt][nt] = __builtin_amdgcn_mfma_f32_16x16x32_bf16(
                    bw2[nt][ks], af[ks], acc[mt][nt], 0, 0, 0);
    }

    float v[4][2][4];
    #pragma unroll
    for (int mt = 0; mt < 4; ++mt) {
        const int node = n0blk + mt * 16 + col;
        float s1 = 0.f, s2 = 0.f;
        #pragma unroll
        for (int nt = 0; nt < 2; ++nt) {
            const int f0 = w * 32 + nt * 16 + quad * 4;
            float4 sk = make_float4(0.f, 0.f, 0.f, 0.f);
            if (node < N) sk = *(const float4*)(skip + (size_t)node * DIM + f0);
            v[mt][nt][0] = acc[mt][nt][0] + b2q[nt].x + sk.x;
            v[mt][nt][1] = acc[mt][nt][1] + b2q[nt].y + sk.y;
            v[mt][nt][2] = acc[mt][nt][2] + b2q[nt].z + sk.z;
            v[mt][nt][3] = acc[mt][nt][3] + b2q[nt].w + sk.w;
            #pragma unroll
            for (int r = 0; r < 4; ++r) {
                s1 += v[mt][nt][r];
                s2 += v[mt][nt][r] * v[mt][nt][r];
            }
        }
        s1 += __shfl_xor(s1, 16); s1 += __shfl_xor(s1, 32);
        s2 += __shfl_xor(s2, 16); s2 += __shfl_xor(s2, 32);
        if (quad == 0) { ls1[w][mt][col] = s1; ls2[w][mt][col] = s2; }
    }
    __syncthreads();

    #pragma unroll
    for (int mt = 0; mt < 4; ++mt) {
        const int node = n0blk + mt * 16 + col;
        if (node >= N) continue;
        const float sum = ls1[0][mt][col] + ls1[1][mt][col] + ls1[2][mt][col] + ls1[3][mt][col];
        const float sq  = ls2[0][mt][col] + ls2[1][mt][col] + ls2[2][mt][col] + ls2[3][mt][col];
        const float mu = sum * (1.f / 128.f);
        const float var = sq * (1.f / 128.f) - mu * mu;
        const float rs = rsqrtf(var + 1e-5f);
        #pragma unroll
        for (int nt = 0; nt < 2; ++nt) {
            const int f0 = w * 32 + nt * 16 + quad * 4;
            const float4 gm = *(const float4*)(gamma + f0);
            const float4 bt = *(const float4*)(beta + f0);
            float4 ov;
            ov.x = (v[mt][nt][0] - mu) * rs * gm.x + bt.x;
            ov.y = (v[mt][nt][1] - mu) * rs * gm.y + bt.y;
            ov.z = (v[mt][nt][2] - mu) * rs * gm.z + bt.z;
            ov.w = (v[mt][nt][3] - mu) * rs * gm.w + bt.w;
            *(float4*)(out + (size_t)node * DIM + f0) = ov;
        }
    }
}

// ---------------------------------------------------------------------------
extern "C" void kernel_launch(void* const* d_in, const int* in_sizes, int n_in,
                              void* d_out, int out_size, void* d_ws, size_t ws_size,
                              hipStream_t stream)
{
    const float* x     = (const float*)d_in[0];
    const int*   eidx  = (const int*)d_in[1];
    const float* Wsrc  = (const float*)d_in[2];
    const float* bsrc  = (const float*)d_in[3];
    const float* Wtgt  = (const float*)d_in[4];
    const float* Wskip = (const float*)d_in[5];
    const float* a0    = (const float*)d_in[6];
    const float* W1    = (const float*)d_in[7];
    const float* b1    = (const float*)d_in[8];
    const float* a1    = (const float*)d_in[9];
    const float* W2    = (const float*)d_in[10];
    const float* b2    = (const float*)d_in[11];
    const float* Wg    = (const float*)d_in[12];
    const float* gamma = (const float*)d_in[13];
    const float* beta  = (const float*)d_in[14];

    const int N = in_sizes[0] / DIM;      // 20000
    const int E = in_sizes[1] / 2;        // 640000
    const int Npad = ((N + 63) / 64) * 64;
    float* out = (float*)d_out;

    char* ws = (char*)d_ws;
    size_t off = 0;
    auto alloc = [&](size_t bytes) -> void* {
        void* p = ws + off;
        off += (bytes + 255) & ~(size_t)255;
        return p;
    };
    unsigned short* msg_src = (unsigned short*)alloc((size_t)N * DIM * 2);
    unsigned short* msg_tgt = (unsigned short*)alloc((size_t)N * DIM * 2);
    float*          skip    = (float*)alloc((size_t)N * DIM * 4);
    float*          gate    = (float*)alloc((size_t)E * 4);
    int*            deg     = (int*)alloc((size_t)N * 4);
    int*            rowptr  = (int*)alloc((size_t)(N + 1) * 4);
    int*            cursor  = (int*)alloc((size_t)N * 4);
    int2*           jip     = (int2*)alloc((size_t)E * 8);
    unsigned short* Wall    = (unsigned short*)alloc((size_t)5 * DIM * DIM * 2);
    float*          w2g     = (float*)alloc((size_t)(DIM + 1) * 4);
    unsigned short* aggh2   = (unsigned short*)alloc((size_t)Npad * DIM * 2);
    unsigned short* h2buf   = (unsigned short*)alloc((size_t)E * DIM * 2);
    (void)ws_size; (void)n_in; (void)out_size;

    hipMemsetAsync(deg, 0, (size_t)N * 4, stream);

    const int nhist = (E + 255) / 256;
    prep_hist_k<<<nhist + (5 * DIM * DIM) / 256 + 1, 256, 0, stream>>>(
        Wsrc, Wtgt, Wskip, W1, W2, b2, Wg, Wall, w2g, eidx, E, deg);

    scan_k<<<1, 256, 0, stream>>>(deg, rowptr, cursor, N);

    const int nscatter = (E + 255) / 256;
    const int nnode = (N + 31) / 32;
    scatter_node_k<<<nscatter + nnode, 256, 0, stream>>>(
        eidx, E, cursor, jip, nscatter,
        x, Wall, bsrc, msg_src, msg_tgt, skip, N);

    const int ntiles = E / 64;
    const int egrid = ntiles < 1024 ? ntiles : 1024;
    edge_mlp_mfma<<<egrid, 256, 0, stream>>>(jip, ntiles, msg_src, msg_tgt, a0,
                                             Wall + 3 * DIM * DIM, b1, a1,
                                             w2g, h2buf, gate);

    aggregate_h2_k<<<(N + 3) / 4, 256, 0, stream>>>(rowptr, gate, h2buf, aggh2, N);

    node_out_k<<<Npad / 64, 256, 0, stream>>>(aggh2, Wall + 4 * DIM * DIM, b2, skip,
                                              gamma, beta, out, N);
}